// Round 8
// baseline (428.543 us; speedup 1.0000x reference)
//
#include <hip/hip_runtime.h>
#include <hip/hip_bf16.h>

static constexpr int cB  = 16;
static constexpr int cS  = 512;
static constexpr int cD  = 256;
static constexpr int cH  = 8;
static constexpr int cDH = 32;

typedef __attribute__((ext_vector_type(8))) short short8v;
typedef __attribute__((ext_vector_type(4))) short short4v;
typedef __attribute__((ext_vector_type(4))) float f32x4;

__device__ __forceinline__ short bfbits(float x) {
    __hip_bfloat16 h = __float2bfloat16(x);
    short s; __builtin_memcpy(&s, &h, 2); return s;
}
__device__ __forceinline__ float bff(short s) {
    __hip_bfloat16 h; __builtin_memcpy(&h, &s, 2); return __bfloat162float(h);
}

// ---------------------------------------------------------------------------
// Projection: C = X @ W^T + b via bf16 hi/lo MFMA (f32-grade accuracy).
// z=0 (Q), z=1 (K): f32 (B,H,S,DH). z=2 (V): bf16 transposed VT[b][h][dh][k].
// ---------------------------------------------------------------------------
__global__ __launch_bounds__(256) void proj_kernel(
    const float* __restrict__ q_in, const float* __restrict__ k_in,
    const float* __restrict__ v_in,
    const float* __restrict__ Wq, const float* __restrict__ bq,
    const float* __restrict__ Wk, const float* __restrict__ bk,
    const float* __restrict__ Wv, const float* __restrict__ bv,
    float* __restrict__ ws)
{
    const int z = blockIdx.y;
    const float* X    = (z == 0) ? q_in : (z == 1) ? k_in : v_in;
    const float* W    = (z == 0) ? Wq   : (z == 1) ? Wk   : Wv;
    const float* bias = (z == 0) ? bq   : (z == 1) ? bk   : bv;
    float* O = ws + (size_t)z * (cB * cS * cD);
    short* VTb = (short*)(ws + 2 * (size_t)cB * cS * cD);

    const int tid  = threadIdx.x;
    const int w    = tid >> 6;
    const int lane = tid & 63;
    const int n16  = lane & 15;
    const int quad = lane >> 4;

    const int i0 = blockIdx.x * 32 + 16 * (w & 1);
    const int j0 = 128 * (w >> 1);

    const float* xrow = X + (size_t)(i0 + n16) * cD + quad * 8;
    short8v a_hi[8], a_lo[8];
#pragma unroll
    for (int c = 0; c < 8; c++) {
        float xa[8];
        *(float4*)&xa[0] = *(const float4*)(xrow + c * 32);
        *(float4*)&xa[4] = *(const float4*)(xrow + c * 32 + 4);
#pragma unroll
        for (int j = 0; j < 8; j++) {
            short hb = bfbits(xa[j]);
            a_hi[c][j] = hb;
            a_lo[c][j] = bfbits(xa[j] - bff(hb));
        }
    }

#pragma unroll
    for (int t = 0; t < 8; t++) {
        const int jb = j0 + t * 16;
        const float* wrow = W + (size_t)(jb + n16) * cD + quad * 8;
        f32x4 acc = (f32x4){0.f, 0.f, 0.f, 0.f};
#pragma unroll
        for (int c = 0; c < 8; c++) {
            float wv_[8];
            *(float4*)&wv_[0] = *(const float4*)(wrow + c * 32);
            *(float4*)&wv_[4] = *(const float4*)(wrow + c * 32 + 4);
            short8v b_hi, b_lo;
#pragma unroll
            for (int j = 0; j < 8; j++) {
                short hb = bfbits(wv_[j]);
                b_hi[j] = hb;
                b_lo[j] = bfbits(wv_[j] - bff(hb));
            }
            acc = __builtin_amdgcn_mfma_f32_16x16x32_bf16(a_hi[c], b_hi, acc, 0, 0, 0);
            acc = __builtin_amdgcn_mfma_f32_16x16x32_bf16(a_hi[c], b_lo, acc, 0, 0, 0);
            acc = __builtin_amdgcn_mfma_f32_16x16x32_bf16(a_lo[c], b_hi, acc, 0, 0, 0);
        }
        const int jg = jb + n16;
        const float bv_ = bias[jg];
        const int h_ = jg >> 5, dh = jg & 31;
        if (z == 2) {
#pragma unroll
            for (int r = 0; r < 4; r++) {
                int gi = i0 + quad * 4 + r;
                int b_ = gi >> 9, s_ = gi & 511;
                VTb[(((size_t)(b_ * cH + h_)) * cDH + dh) * cS + s_] =
                    bfbits(acc[r] + bv_);
            }
        } else {
#pragma unroll
            for (int r = 0; r < 4; r++) {
                int gi = i0 + quad * 4 + r;
                int b_ = gi >> 9, s_ = gi & 511;
                O[(((size_t)(b_ * cH + h_)) * cS + s_) * cDH + dh] = acc[r] + bv_;
            }
        }
    }
}

// ---------------------------------------------------------------------------
// Ev kernel: Ev[b][q][k] = Bc*time_attn + Cc*rel_attn (head-independent),
// bf16. One wave per (b,q) row. Triangular predicated loads.
// ---------------------------------------------------------------------------
__global__ __launch_bounds__(256) void ev_kernel(
    const float* __restrict__ rel, const float* __restrict__ ts,
    const float* __restrict__ l1p, const float* __restrict__ l2p,
    short* __restrict__ Evb)
{
    const int w = threadIdx.x >> 6, lane = threadIdx.x & 63;
    const int row = blockIdx.x * 4 + w;
    const int q = row & 511;
    const float* tr = ts  + (size_t)row * cS;
    const float* rr = rel + (size_t)row * cS;
    const float l1 = l1p[0], l2 = l2p[0];
    const float Bc = (1.f - l1) * l2;
    const float Cc = l1;

    float tv[8], rv[8];
    float tmax = -1e30f, rmax = -1e30f;
#pragma unroll
    for (int j = 0; j < 8; j++) {
        int k = lane + 64 * j;
        float tl_ = (k <= q) ? tr[k] : 0.f;
        float r   = (k >  q) ? rr[k] : 0.f;
        tv[j] = (k <= q) ? __expf(-fabsf(tl_)) : -1e30f;
        rv[j] = (k > q && r != 0.f) ? r : -10000.f;
        tmax = fmaxf(tmax, tv[j]);
        rmax = fmaxf(rmax, rv[j]);
    }
#pragma unroll
    for (int m = 1; m < 64; m <<= 1) {
        tmax = fmaxf(tmax, __shfl_xor(tmax, m, 64));
        rmax = fmaxf(rmax, __shfl_xor(rmax, m, 64));
    }
    float te[8], re[8];
    float tsum = 0.f, rsum = 0.f;
#pragma unroll
    for (int j = 0; j < 8; j++) {
        te[j] = (tv[j] > -1e29f) ? __expf(tv[j] - tmax) : 0.f;
        re[j] = __expf(rv[j] - rmax);
        tsum += te[j]; rsum += re[j];
    }
#pragma unroll
    for (int m = 1; m < 64; m <<= 1) {
        tsum += __shfl_xor(tsum, m, 64);
        rsum += __shfl_xor(rsum, m, 64);
    }
    const float ti = Bc / tsum, ri = Cc / rsum;
#pragma unroll
    for (int j = 0; j < 8; j++) {
        int k = lane + 64 * j;
        Evb[(size_t)row * cS + k] = bfbits(te[j] * ti + re[j] * ri);
    }
}

// ===========================================================================
// SPLIT PATH (used when ws_size is large enough for a 67 MB P_soft buffer):
// attn3 computes QK^T + softmax + PV + out, writes bf16 P_soft to ws instead
// of the 134 MB f32 prob; prob_kernel streams prob = P_soft + Ev separately.
// ===========================================================================
__global__ __launch_bounds__(256, 4) void attn3_kernel(
    const float* __restrict__ ws, const short* __restrict__ Evb,
    short* __restrict__ Pg,
    const float* __restrict__ l1p, const float* __restrict__ l2p,
    float* __restrict__ out)
{
    constexpr int PS = 536;
    __shared__ short Pl[32 * PS];
    __shared__ float redM[2][32];
    __shared__ float redS[2][32];

    const int tid  = threadIdx.x;
    const int w    = tid >> 6;
    const int lane = tid & 63;
    const int n16  = lane & 15;
    const int quad = lane >> 4;

    const int flat = blockIdx.y * gridDim.x + blockIdx.x;
    const int xcd  = flat & 7;
    const int slot = flat >> 3;
    const int b  = xcd + 8 * (slot >> 7);
    const int h  = (slot >> 4) & 7;
    const int qt = slot & 15;
    const size_t bh = (size_t)b * cH + h;
    const int q0 = qt * 32;

    const float* qh = ws;
    const float* kh = ws + (size_t)cB * cS * cD;
    const short* VTb = (const short*)(ws + 2 * (size_t)cB * cS * cD);

    const float l1 = l1p[0], l2 = l2p[0];
    const float Ac = (1.f - l1) * (1.f - l2);

    const int qhH = w & 1;
    const int kh2 = w >> 1;
    const int kbase = 256 * kh2;

    const int rowA = q0 + 16 * qhH + n16;
    const float* qrow = qh + (bh * cS + rowA) * cDH + quad * 8;
    float qa[8];
    *(float4*)&qa[0] = *(const float4*)qrow;
    *(float4*)&qa[4] = *(const float4*)(qrow + 4);
    short8v a_hi, a_lo;
#pragma unroll
    for (int j = 0; j < 8; j++) {
        short hbits = bfbits(qa[j]);
        a_hi[j] = hbits;
        a_lo[j] = bfbits(qa[j] - bff(hbits));
    }

    f32x4 acc[16];
#pragma unroll
    for (int t = 0; t < 16; t++) acc[t] = (f32x4){0.f, 0.f, 0.f, 0.f};

    const int tl = (kbase <= q0 + 31) ? min(15, (q0 + 31 - kbase) >> 4) : -1;
    for (int t = 0; t <= tl; t++) {
        const float* krow = kh + (bh * cS + kbase + 16 * t + n16) * cDH + quad * 8;
        float kb[8];
        *(float4*)&kb[0] = *(const float4*)krow;
        *(float4*)&kb[4] = *(const float4*)(krow + 4);
        short8v b_hi, b_lo;
#pragma unroll
        for (int j = 0; j < 8; j++) {
            short hbits = bfbits(kb[j]);
            b_hi[j] = hbits;
            b_lo[j] = bfbits(kb[j] - bff(hbits));
        }
        acc[t] = __builtin_amdgcn_mfma_f32_16x16x32_bf16(a_hi, b_hi, acc[t], 0, 0, 0);
        acc[t] = __builtin_amdgcn_mfma_f32_16x16x32_bf16(a_hi, b_lo, acc[t], 0, 0, 0);
        acc[t] = __builtin_amdgcn_mfma_f32_16x16x32_bf16(a_lo, b_hi, acc[t], 0, 0, 0);
    }

    const float scale = 0.17677669529663687f;
    const int rowDl = 16 * qhH + quad * 4;
    float Mx0 = -1e30f, Mx1 = -1e30f, Mx2 = -1e30f, Mx3 = -1e30f;
#pragma unroll
    for (int t = 0; t < 16; t++) {
        const int kg = kbase + 16 * t + n16;
        const int rg = q0 + rowDl;
        float s0 = (kg <= rg + 0) ? acc[t][0] * scale : -1e30f;
        float s1 = (kg <= rg + 1) ? acc[t][1] * scale : -1e30f;
        float s2 = (kg <= rg + 2) ? acc[t][2] * scale : -1e30f;
        float s3 = (kg <= rg + 3) ? acc[t][3] * scale : -1e30f;
        acc[t][0] = s0; acc[t][1] = s1; acc[t][2] = s2; acc[t][3] = s3;
        Mx0 = fmaxf(Mx0, s0); Mx1 = fmaxf(Mx1, s1);
        Mx2 = fmaxf(Mx2, s2); Mx3 = fmaxf(Mx3, s3);
    }
#pragma unroll
    for (int m = 1; m < 16; m <<= 1) {
        Mx0 = fmaxf(Mx0, __shfl_xor(Mx0, m, 64));
        Mx1 = fmaxf(Mx1, __shfl_xor(Mx1, m, 64));
        Mx2 = fmaxf(Mx2, __shfl_xor(Mx2, m, 64));
        Mx3 = fmaxf(Mx3, __shfl_xor(Mx3, m, 64));
    }
    if (n16 == 0) {
        redM[kh2][rowDl + 0] = Mx0; redM[kh2][rowDl + 1] = Mx1;
        redM[kh2][rowDl + 2] = Mx2; redM[kh2][rowDl + 3] = Mx3;
    }
    __syncthreads();
    float Mg0 = fmaxf(redM[0][rowDl + 0], redM[1][rowDl + 0]);
    float Mg1 = fmaxf(redM[0][rowDl + 1], redM[1][rowDl + 1]);
    float Mg2 = fmaxf(redM[0][rowDl + 2], redM[1][rowDl + 2]);
    float Mg3 = fmaxf(redM[0][rowDl + 3], redM[1][rowDl + 3]);

    float S0 = 0.f, S1 = 0.f, S2 = 0.f, S3 = 0.f;
#pragma unroll
    for (int t = 0; t < 16; t++) {
        float e0 = __expf(acc[t][0] - Mg0);
        float e1 = __expf(acc[t][1] - Mg1);
        float e2 = __expf(acc[t][2] - Mg2);
        float e3 = __expf(acc[t][3] - Mg3);
        acc[t][0] = e0; acc[t][1] = e1; acc[t][2] = e2; acc[t][3] = e3;
        S0 += e0; S1 += e1; S2 += e2; S3 += e3;
    }
#pragma unroll
    for (int m = 1; m < 16; m <<= 1) {
        S0 += __shfl_xor(S0, m, 64); S1 += __shfl_xor(S1, m, 64);
        S2 += __shfl_xor(S2, m, 64); S3 += __shfl_xor(S3, m, 64);
    }
    if (n16 == 0) {
        redS[kh2][rowDl + 0] = S0; redS[kh2][rowDl + 1] = S1;
        redS[kh2][rowDl + 2] = S2; redS[kh2][rowDl + 3] = S3;
    }
    __syncthreads();
    const float i0 = Ac / (redS[0][rowDl + 0] + redS[1][rowDl + 0]);
    const float i1 = Ac / (redS[0][rowDl + 1] + redS[1][rowDl + 1]);
    const float i2 = Ac / (redS[0][rowDl + 2] + redS[1][rowDl + 2]);
    const float i3 = Ac / (redS[0][rowDl + 3] + redS[1][rowDl + 3]);

#pragma unroll
    for (int t = 0; t < 16; t++) {
        const int col = kbase + 16 * t + n16;
        Pl[(rowDl + 0) * PS + col] = bfbits(acc[t][0] * i0);
        Pl[(rowDl + 1) * PS + col] = bfbits(acc[t][1] * i1);
        Pl[(rowDl + 2) * PS + col] = bfbits(acc[t][2] * i2);
        Pl[(rowDl + 3) * PS + col] = bfbits(acc[t][3] * i3);
    }
    __syncthreads();

    // ---- P_soft -> global (bf16, coalesced, cached ws) + Ev blend into LDS
    // for PV. NO 134 MB f32 prob store here (moved to prob_kernel).
#pragma unroll
    for (int it = 0; it < 16; it++) {
        const int idx = it * 256 + tid;
        const int r = idx >> 7;
        const int c0 = (idx & 127) * 4;
        short* pp = &Pl[r * PS + c0];
        short4v pv = *(short4v*)pp;
        *(short4v*)(Pg + ((bh * cS + q0 + r)) * cS + c0) = pv;
        const short4v ev = *(const short4v*)(Evb + ((size_t)(b * cS + q0 + r)) * cS + c0);
#pragma unroll
        for (int j = 0; j < 4; j++) pv[j] = bfbits(bff(pv[j]) + bff(ev[j]));
        *(short4v*)pp = pv;
    }
    __syncthreads();

    // ---- PV with precomputed bf16 V^T ----
    const int dhT = w & 1, qT = w >> 1;
    const int dhA = 16 * dhT + n16;
    const short* vtrow = VTb + (bh * cDH + dhA) * cS;
    f32x4 oacc = (f32x4){0.f, 0.f, 0.f, 0.f};
#pragma unroll
    for (int k0 = 0; k0 < cS; k0 += 32) {
        short8v av = *(const short8v*)(vtrow + k0 + quad * 8);
        short8v bv = *(short8v*)&Pl[(16 * qT + n16) * PS + k0 + quad * 8];
        oacc = __builtin_amdgcn_mfma_f32_16x16x32_bf16(av, bv, oacc, 0, 0, 0);
    }
    const int qg = q0 + 16 * qT + n16;
    const int dhD = 16 * dhT + quad * 4;
    float* op = out + ((size_t)b * cS + qg) * cD + h * cDH + dhD;
    __builtin_nontemporal_store(oacc, (f32x4*)op);
}

// ---------------------------------------------------------------------------
// prob stream kernel: prob[bh][q][k] = f32(P_soft) + f32(Ev). Barrier-free,
// full occupancy, perfectly coalesced. Its duration directly measures the
// achievable d_out write rate for the known-real 134 MB.
// ---------------------------------------------------------------------------
__global__ __launch_bounds__(256) void prob_kernel(
    const short* __restrict__ Pg, const short* __restrict__ Evb,
    float* __restrict__ prob)
{
    const int tid = threadIdx.x;
    const int flat = blockIdx.y * gridDim.x + blockIdx.x;
    const int xcd  = flat & 7;
    const int slot = flat >> 3;
    const int b  = xcd + 8 * (slot >> 7);
    const int h  = (slot >> 4) & 7;
    const int qt = slot & 15;
    const size_t bh = (size_t)b * cH + h;
    const int q0 = qt * 32;

#pragma unroll
    for (int it = 0; it < 16; it++) {
        const int idx = it * 256 + tid;
        const int r = idx >> 7;
        const int c0 = (idx & 127) * 4;
        const short4v pv = *(const short4v*)(Pg + (bh * cS + q0 + r) * cS + c0);
        const short4v ev = *(const short4v*)(Evb + ((size_t)(b * cS + q0 + r)) * cS + c0);
        f32x4 o;
#pragma unroll
        for (int j = 0; j < 4; j++) o[j] = bff(pv[j]) + bff(ev[j]);
        __builtin_nontemporal_store(o, (f32x4*)(prob + (bh * cS + q0 + r) * cS + c0));
    }
}

// ===========================================================================
// FALLBACK PATH (ws too small): exact round-5 fused attn2.
// ===========================================================================
__global__ __launch_bounds__(256, 4) void attn2_kernel(
    const float* __restrict__ ws, const short* __restrict__ Evb,
    const float* __restrict__ l1p, const float* __restrict__ l2p,
    float* __restrict__ out, float* __restrict__ prob)
{
    constexpr int PS = 536;
    __shared__ short Pl[32 * PS];
    __shared__ float redM[2][32];
    __shared__ float redS[2][32];

    const int tid  = threadIdx.x;
    const int w    = tid >> 6;
    const int lane = tid & 63;
    const int n16  = lane & 15;
    const int quad = lane >> 4;

    const int flat = blockIdx.y * gridDim.x + blockIdx.x;
    const int xcd  = flat & 7;
    const int slot = flat >> 3;
    const int b  = xcd + 8 * (slot >> 7);
    const int h  = (slot >> 4) & 7;
    const int qt = slot & 15;
    const size_t bh = (size_t)b * cH + h;
    const int q0 = qt * 32;

    const float* qh = ws;
    const float* kh = ws + (size_t)cB * cS * cD;
    const short* VTb = (const short*)(ws + 2 * (size_t)cB * cS * cD);

    const float l1 = l1p[0], l2 = l2p[0];
    const float Ac = (1.f - l1) * (1.f - l2);

    const int qhH = w & 1;
    const int kh2 = w >> 1;
    const int kbase = 256 * kh2;

    const int rowA = q0 + 16 * qhH + n16;
    const float* qrow = qh + (bh * cS + rowA) * cDH + quad * 8;
    float qa[8];
    *(float4*)&qa[0] = *(const float4*)qrow;
    *(float4*)&qa[4] = *(const float4*)(qrow + 4);
    short8v a_hi, a_lo;
#pragma unroll
    for (int j = 0; j < 8; j++) {
        short hbits = bfbits(qa[j]);
        a_hi[j] = hbits;
        a_lo[j] = bfbits(qa[j] - bff(hbits));
    }

    f32x4 acc[16];
#pragma unroll
    for (int t = 0; t < 16; t++) acc[t] = (f32x4){0.f, 0.f, 0.f, 0.f};

    const int tl = (kbase <= q0 + 31) ? min(15, (q0 + 31 - kbase) >> 4) : -1;
    for (int t = 0; t <= tl; t++) {
        const float* krow = kh + (bh * cS + kbase + 16 * t + n16) * cDH + quad * 8;
        float kb[8];
        *(float4*)&kb[0] = *(const float4*)krow;
        *(float4*)&kb[4] = *(const float4*)(krow + 4);
        short8v b_hi, b_lo;
#pragma unroll
        for (int j = 0; j < 8; j++) {
            short hbits = bfbits(kb[j]);
            b_hi[j] = hbits;
            b_lo[j] = bfbits(kb[j] - bff(hbits));
        }
        acc[t] = __builtin_amdgcn_mfma_f32_16x16x32_bf16(a_hi, b_hi, acc[t], 0, 0, 0);
        acc[t] = __builtin_amdgcn_mfma_f32_16x16x32_bf16(a_hi, b_lo, acc[t], 0, 0, 0);
        acc[t] = __builtin_amdgcn_mfma_f32_16x16x32_bf16(a_lo, b_hi, acc[t], 0, 0, 0);
    }

    const float scale = 0.17677669529663687f;
    const int rowDl = 16 * qhH + quad * 4;
    float Mx0 = -1e30f, Mx1 = -1e30f, Mx2 = -1e30f, Mx3 = -1e30f;
#pragma unroll
    for (int t = 0; t < 16; t++) {
        const int kg = kbase + 16 * t + n16;
        const int rg = q0 + rowDl;
        float s0 = (kg <= rg + 0) ? acc[t][0] * scale : -1e30f;
        float s1 = (kg <= rg + 1) ? acc[t][1] * scale : -1e30f;
        float s2 = (kg <= rg + 2) ? acc[t][2] * scale : -1e30f;
        float s3 = (kg <= rg + 3) ? acc[t][3] * scale : -1e30f;
        acc[t][0] = s0; acc[t][1] = s1; acc[t][2] = s2; acc[t][3] = s3;
        Mx0 = fmaxf(Mx0, s0); Mx1 = fmaxf(Mx1, s1);
        Mx2 = fmaxf(Mx2, s2); Mx3 = fmaxf(Mx3, s3);
    }
#pragma unroll
    for (int m = 1; m < 16; m <<= 1) {
        Mx0 = fmaxf(Mx0, __shfl_xor(Mx0, m, 64));
        Mx1 = fmaxf(Mx1, __shfl_xor(Mx1, m, 64));
        Mx2 = fmaxf(Mx2, __shfl_xor(Mx2, m, 64));
        Mx3 = fmaxf(Mx3, __shfl_xor(Mx3, m, 64));
    }
    if (n16 == 0) {
        redM[kh2][rowDl + 0] = Mx0; redM[kh2][rowDl + 1] = Mx1;
        redM[kh2][rowDl + 2] = Mx2; redM[kh2][rowDl + 3] = Mx3;
    }
    __syncthreads();
    float Mg0 = fmaxf(redM[0][rowDl + 0], redM[1][rowDl + 0]);
    float Mg1 = fmaxf(redM[0][rowDl + 1], redM[1][rowDl + 1]);
    float Mg2 = fmaxf(redM[0][rowDl + 2], redM[1][rowDl + 2]);
    float Mg3 = fmaxf(redM[0][rowDl + 3], redM[1][rowDl + 3]);

    float S0 = 0.f, S1 = 0.f, S2 = 0.f, S3 = 0.f;
#pragma unroll
    for (int t = 0; t < 16; t++) {
        float e0 = __expf(acc[t][0] - Mg0);
        float e1 = __expf(acc[t][1] - Mg1);
        float e2 = __expf(acc[t][2] - Mg2);
        float e3 = __expf(acc[t][3] - Mg3);
        acc[t][0] = e0; acc[t][1] = e1; acc[t][2] = e2; acc[t][3] = e3;
        S0 += e0; S1 += e1; S2 += e2; S3 += e3;
    }
#pragma unroll
    for (int m = 1; m < 16; m <<= 1) {
        S0 += __shfl_xor(S0, m, 64); S1 += __shfl_xor(S1, m, 64);
        S2 += __shfl_xor(S2, m, 64); S3 += __shfl_xor(S3, m, 64);
    }
    if (n16 == 0) {
        redS[kh2][rowDl + 0] = S0; redS[kh2][rowDl + 1] = S1;
        redS[kh2][rowDl + 2] = S2; redS[kh2][rowDl + 3] = S3;
    }
    __syncthreads();
    const float i0 = Ac / (redS[0][rowDl + 0] + redS[1][rowDl + 0]);
    const float i1 = Ac / (redS[0][rowDl + 1] + redS[1][rowDl + 1]);
    const float i2 = Ac / (redS[0][rowDl + 2] + redS[1][rowDl + 2]);
    const float i3 = Ac / (redS[0][rowDl + 3] + redS[1][rowDl + 3]);

#pragma unroll
    for (int t = 0; t < 16; t++) {
        const int col = kbase + 16 * t + n16;
        Pl[(rowDl + 0) * PS + col] = bfbits(acc[t][0] * i0);
        Pl[(rowDl + 1) * PS + col] = bfbits(acc[t][1] * i1);
        Pl[(rowDl + 2) * PS + col] = bfbits(acc[t][2] * i2);
        Pl[(rowDl + 3) * PS + col] = bfbits(acc[t][3] * i3);
    }
    __syncthreads();

#pragma unroll
    for (int it = 0; it < 16; it++) {
        const int idx = it * 256 + tid;
        const int r = idx >> 7;
        const int c0 = (idx & 127) * 4;
        short* pp = &Pl[r * PS + c0];
        short4v pv = *(short4v*)pp;
        const short4v ev = *(const short4v*)(Evb + ((size_t)(b * cS + q0 + r)) * cS + c0);
        f32x4 o;
#pragma unroll
        for (int j = 0; j < 4; j++) o[j] = bff(pv[j]) + bff(ev[j]);
        __builtin_nontemporal_store(o, (f32x4*)(prob + (bh * cS + q0 + r) * cS + c0));
#pragma unroll
        for (int j = 0; j < 4; j++) pv[j] = bfbits(o[j]);
        *(short4v*)pp = pv;
    }
    __syncthreads();

    const int dhT = w & 1, qT = w >> 1;
    const int dhA = 16 * dhT + n16;
    const short* vtrow = VTb + (bh * cDH + dhA) * cS;
    f32x4 oacc = (f32x4){0.f, 0.f, 0.f, 0.f};
#pragma unroll
    for (int k0 = 0; k0 < cS; k0 += 32) {
        short8v av = *(const short8v*)(vtrow + k0 + quad * 8);
        short8v bv = *(short8v*)&Pl[(16 * qT + n16) * PS + k0 + quad * 8];
        oacc = __builtin_amdgcn_mfma_f32_16x16x32_bf16(av, bv, oacc, 0, 0, 0);
    }
    const int qg = q0 + 16 * qT + n16;
    const int dhD = 16 * dhT + quad * 4;
    float* op = out + ((size_t)b * cS + qg) * cD + h * cDH + dhD;
    __builtin_nontemporal_store(oacc, (f32x4*)op);
}

extern "C" void kernel_launch(void* const* d_in, const int* in_sizes, int n_in,
                              void* d_out, int out_size, void* d_ws, size_t ws_size,
                              hipStream_t stream) {
    const float* query = (const float*)d_in[0];
    const float* key   = (const float*)d_in[1];
    const float* value = (const float*)d_in[2];
    const float* rel   = (const float*)d_in[3];
    const float* tsp   = (const float*)d_in[4];
    const float* l1 = (const float*)d_in[6];
    const float* l2 = (const float*)d_in[7];
    const float* Wq = (const float*)d_in[8];
    const float* bq = (const float*)d_in[9];
    const float* Wk = (const float*)d_in[10];
    const float* bk = (const float*)d_in[11];
    const float* Wv = (const float*)d_in[12];
    const float* bv = (const float*)d_in[13];

    float* ws   = (float*)d_ws;
    short* Evb  = (short*)(ws + 3 * (size_t)cB * cS * cD);   // bf16, 8.4 MB
    short* Pg   = Evb + (size_t)cB * cS * cS;                // bf16, 67 MB
    float* out  = (float*)d_out;
    float* prob = out + (size_t)cB * cS * cD;

    // bytes needed for split path: 3 f32 slots + Evb + Pg
    const size_t need = (size_t)3 * cB * cS * cD * 4
                      + (size_t)cB * cS * cS * 2
                      + (size_t)cB * cH * cS * cS * 2;       // 100,663,296

    proj_kernel<<<dim3(256, 3), 256, 0, stream>>>(query, key, value,
                                                  Wq, bq, Wk, bk, Wv, bv, ws);
    ev_kernel<<<dim3(2048), 256, 0, stream>>>(rel, tsp, l1, l2, Evb);
    if (ws_size >= need) {
        attn3_kernel<<<dim3(16, 128), 256, 0, stream>>>(ws, Evb, Pg, l1, l2, out);
        prob_kernel<<<dim3(16, 128), 256, 0, stream>>>(Pg, Evb, prob);
    } else {
        attn2_kernel<<<dim3(16, 128), 256, 0, stream>>>(ws, Evb, l1, l2, out, prob);
    }
}

// Round 9
// 296.746 us; speedup vs baseline: 1.4441x; 1.4441x over previous
//
#include <hip/hip_runtime.h>
#include <hip/hip_bf16.h>

static constexpr int cB  = 16;
static constexpr int cS  = 512;
static constexpr int cD  = 256;
static constexpr int cH  = 8;
static constexpr int cDH = 32;

typedef __attribute__((ext_vector_type(8))) short short8v;
typedef __attribute__((ext_vector_type(4))) short short4v;
typedef __attribute__((ext_vector_type(4))) float f32x4;

__device__ __forceinline__ short bfbits(float x) {
    __hip_bfloat16 h = __float2bfloat16(x);
    short s; __builtin_memcpy(&s, &h, 2); return s;
}
__device__ __forceinline__ float bff(short s) {
    __hip_bfloat16 h; __builtin_memcpy(&h, &s, 2); return __bfloat162float(h);
}

// ---------------------------------------------------------------------------
// Projection: C = X @ W^T + b via bf16 hi/lo MFMA (f32-grade accuracy).
// z=0 (Q), z=1 (K): f32 (B,H,S,DH). z=2 (V): bf16 transposed VT[b][h][dh][k].
// ---------------------------------------------------------------------------
__global__ __launch_bounds__(256) void proj_kernel(
    const float* __restrict__ q_in, const float* __restrict__ k_in,
    const float* __restrict__ v_in,
    const float* __restrict__ Wq, const float* __restrict__ bq,
    const float* __restrict__ Wk, const float* __restrict__ bk,
    const float* __restrict__ Wv, const float* __restrict__ bv,
    float* __restrict__ ws)
{
    const int z = blockIdx.y;
    const float* X    = (z == 0) ? q_in : (z == 1) ? k_in : v_in;
    const float* W    = (z == 0) ? Wq   : (z == 1) ? Wk   : Wv;
    const float* bias = (z == 0) ? bq   : (z == 1) ? bk   : bv;
    float* O = ws + (size_t)z * (cB * cS * cD);
    short* VTb = (short*)(ws + 2 * (size_t)cB * cS * cD);

    const int tid  = threadIdx.x;
    const int w    = tid >> 6;
    const int lane = tid & 63;
    const int n16  = lane & 15;
    const int quad = lane >> 4;

    const int i0 = blockIdx.x * 32 + 16 * (w & 1);
    const int j0 = 128 * (w >> 1);

    const float* xrow = X + (size_t)(i0 + n16) * cD + quad * 8;
    short8v a_hi[8], a_lo[8];
#pragma unroll
    for (int c = 0; c < 8; c++) {
        float xa[8];
        *(float4*)&xa[0] = *(const float4*)(xrow + c * 32);
        *(float4*)&xa[4] = *(const float4*)(xrow + c * 32 + 4);
#pragma unroll
        for (int j = 0; j < 8; j++) {
            short hb = bfbits(xa[j]);
            a_hi[c][j] = hb;
            a_lo[c][j] = bfbits(xa[j] - bff(hb));
        }
    }

#pragma unroll
    for (int t = 0; t < 8; t++) {
        const int jb = j0 + t * 16;
        const float* wrow = W + (size_t)(jb + n16) * cD + quad * 8;
        f32x4 acc = (f32x4){0.f, 0.f, 0.f, 0.f};
#pragma unroll
        for (int c = 0; c < 8; c++) {
            float wv_[8];
            *(float4*)&wv_[0] = *(const float4*)(wrow + c * 32);
            *(float4*)&wv_[4] = *(const float4*)(wrow + c * 32 + 4);
            short8v b_hi, b_lo;
#pragma unroll
            for (int j = 0; j < 8; j++) {
                short hb = bfbits(wv_[j]);
                b_hi[j] = hb;
                b_lo[j] = bfbits(wv_[j] - bff(hb));
            }
            acc = __builtin_amdgcn_mfma_f32_16x16x32_bf16(a_hi[c], b_hi, acc, 0, 0, 0);
            acc = __builtin_amdgcn_mfma_f32_16x16x32_bf16(a_hi[c], b_lo, acc, 0, 0, 0);
            acc = __builtin_amdgcn_mfma_f32_16x16x32_bf16(a_lo[c], b_hi, acc, 0, 0, 0);
        }
        const int jg = jb + n16;
        const float bv_ = bias[jg];
        const int h_ = jg >> 5, dh = jg & 31;
        if (z == 2) {
#pragma unroll
            for (int r = 0; r < 4; r++) {
                int gi = i0 + quad * 4 + r;
                int b_ = gi >> 9, s_ = gi & 511;
                VTb[(((size_t)(b_ * cH + h_)) * cDH + dh) * cS + s_] =
                    bfbits(acc[r] + bv_);
            }
        } else {
#pragma unroll
            for (int r = 0; r < 4; r++) {
                int gi = i0 + quad * 4 + r;
                int b_ = gi >> 9, s_ = gi & 511;
                O[(((size_t)(b_ * cH + h_)) * cS + s_) * cDH + dh] = acc[r] + bv_;
            }
        }
    }
}

// ---------------------------------------------------------------------------
// Ev kernel: Ev[b][q][k] = Bc*time_attn + Cc*rel_attn (head-independent),
// bf16. One wave per (b,q) row. Triangular predicated loads.
// ---------------------------------------------------------------------------
__global__ __launch_bounds__(256) void ev_kernel(
    const float* __restrict__ rel, const float* __restrict__ ts,
    const float* __restrict__ l1p, const float* __restrict__ l2p,
    short* __restrict__ Evb)
{
    const int w = threadIdx.x >> 6, lane = threadIdx.x & 63;
    const int row = blockIdx.x * 4 + w;
    const int q = row & 511;
    const float* tr = ts  + (size_t)row * cS;
    const float* rr = rel + (size_t)row * cS;
    const float l1 = l1p[0], l2 = l2p[0];
    const float Bc = (1.f - l1) * l2;
    const float Cc = l1;

    float tv[8], rv[8];
    float tmax = -1e30f, rmax = -1e30f;
#pragma unroll
    for (int j = 0; j < 8; j++) {
        int k = lane + 64 * j;
        float tl_ = (k <= q) ? tr[k] : 0.f;
        float r   = (k >  q) ? rr[k] : 0.f;
        tv[j] = (k <= q) ? __expf(-fabsf(tl_)) : -1e30f;
        rv[j] = (k > q && r != 0.f) ? r : -10000.f;
        tmax = fmaxf(tmax, tv[j]);
        rmax = fmaxf(rmax, rv[j]);
    }
#pragma unroll
    for (int m = 1; m < 64; m <<= 1) {
        tmax = fmaxf(tmax, __shfl_xor(tmax, m, 64));
        rmax = fmaxf(rmax, __shfl_xor(rmax, m, 64));
    }
    float te[8], re[8];
    float tsum = 0.f, rsum = 0.f;
#pragma unroll
    for (int j = 0; j < 8; j++) {
        te[j] = (tv[j] > -1e29f) ? __expf(tv[j] - tmax) : 0.f;
        re[j] = __expf(rv[j] - rmax);
        tsum += te[j]; rsum += re[j];
    }
#pragma unroll
    for (int m = 1; m < 64; m <<= 1) {
        tsum += __shfl_xor(tsum, m, 64);
        rsum += __shfl_xor(rsum, m, 64);
    }
    const float ti = Bc / tsum, ri = Cc / rsum;
#pragma unroll
    for (int j = 0; j < 8; j++) {
        int k = lane + 64 * j;
        Evb[(size_t)row * cS + k] = bfbits(te[j] * ti + re[j] * ri);
    }
}

// ---------------------------------------------------------------------------
// Attention v6 (fused): the QK^T loop is now FULLY UNROLLED with a
// wave-uniform skip predicate. Previously `for (t=0; t<=tl; t++)` had a
// RUNTIME bound -> acc[16] was runtime-indexed -> the whole 256 B/lane
// accumulator array lived in SCRATCH (VGPR_Count=52 despite 64 regs of
// accumulator; ~444 MB/dispatch of hidden scratch write traffic = the
// constant WRITE_SIZE excess across rounds 0-8). Static indexing puts acc
// in registers; `if (t <= tl)` keeps the causal work-skip as a free
// scalar branch.
// ---------------------------------------------------------------------------
__global__ __launch_bounds__(256, 4) void attn2_kernel(
    const float* __restrict__ ws, const short* __restrict__ Evb,
    const float* __restrict__ l1p, const float* __restrict__ l2p,
    float* __restrict__ out, float* __restrict__ prob)
{
    constexpr int PS = 536;
    __shared__ short Pl[32 * PS];
    __shared__ float redM[2][32];
    __shared__ float redS[2][32];

    const int tid  = threadIdx.x;
    const int w    = tid >> 6;
    const int lane = tid & 63;
    const int n16  = lane & 15;
    const int quad = lane >> 4;

    // XCD-aware remap: all 128 blocks of batch b land on XCD b%8.
    const int flat = blockIdx.y * gridDim.x + blockIdx.x;
    const int xcd  = flat & 7;
    const int slot = flat >> 3;
    const int b  = xcd + 8 * (slot >> 7);
    const int h  = (slot >> 4) & 7;
    const int qt = slot & 15;
    const size_t bh = (size_t)b * cH + h;
    const int q0 = qt * 32;

    const float* qh = ws;
    const float* kh = ws + (size_t)cB * cS * cD;
    const short* VTb = (const short*)(ws + 2 * (size_t)cB * cS * cD);

    const float l1 = l1p[0], l2 = l2p[0];
    const float Ac = (1.f - l1) * (1.f - l2);

    const int qhH = w & 1;
    const int kh2 = w >> 1;
    const int kbase = 256 * kh2;

    // ---- A fragment: Q rows (hi/lo bf16 split) ----
    const int rowA = q0 + 16 * qhH + n16;
    const float* qrow = qh + (bh * cS + rowA) * cDH + quad * 8;
    float qa[8];
    *(float4*)&qa[0] = *(const float4*)qrow;
    *(float4*)&qa[4] = *(const float4*)(qrow + 4);
    short8v a_hi, a_lo;
#pragma unroll
    for (int j = 0; j < 8; j++) {
        short hbits = bfbits(qa[j]);
        a_hi[j] = hbits;
        a_lo[j] = bfbits(qa[j] - bff(hbits));
    }

    // ---- QK^T: 16 key tiles, statically unrolled, uniform skip ----
    const int tl = (kbase <= q0 + 31) ? min(15, (q0 + 31 - kbase) >> 4) : -1;
    f32x4 acc[16];
#pragma unroll
    for (int t = 0; t < 16; t++) {
        acc[t] = (f32x4){0.f, 0.f, 0.f, 0.f};
        if (t <= tl) {
            const float* krow = kh + (bh * cS + kbase + 16 * t + n16) * cDH + quad * 8;
            float kb[8];
            *(float4*)&kb[0] = *(const float4*)krow;
            *(float4*)&kb[4] = *(const float4*)(krow + 4);
            short8v b_hi, b_lo;
#pragma unroll
            for (int j = 0; j < 8; j++) {
                short hbits = bfbits(kb[j]);
                b_hi[j] = hbits;
                b_lo[j] = bfbits(kb[j] - bff(hbits));
            }
            acc[t] = __builtin_amdgcn_mfma_f32_16x16x32_bf16(a_hi, b_hi, acc[t], 0, 0, 0);
            acc[t] = __builtin_amdgcn_mfma_f32_16x16x32_bf16(a_hi, b_lo, acc[t], 0, 0, 0);
            acc[t] = __builtin_amdgcn_mfma_f32_16x16x32_bf16(a_lo, b_hi, acc[t], 0, 0, 0);
        }
    }

    // ---- mask + scale + row max ----
    const float scale = 0.17677669529663687f;
    const int rowDl = 16 * qhH + quad * 4;
    float Mx0 = -1e30f, Mx1 = -1e30f, Mx2 = -1e30f, Mx3 = -1e30f;
#pragma unroll
    for (int t = 0; t < 16; t++) {
        const int kg = kbase + 16 * t + n16;
        const int rg = q0 + rowDl;
        float s0 = (kg <= rg + 0) ? acc[t][0] * scale : -1e30f;
        float s1 = (kg <= rg + 1) ? acc[t][1] * scale : -1e30f;
        float s2 = (kg <= rg + 2) ? acc[t][2] * scale : -1e30f;
        float s3 = (kg <= rg + 3) ? acc[t][3] * scale : -1e30f;
        acc[t][0] = s0; acc[t][1] = s1; acc[t][2] = s2; acc[t][3] = s3;
        Mx0 = fmaxf(Mx0, s0); Mx1 = fmaxf(Mx1, s1);
        Mx2 = fmaxf(Mx2, s2); Mx3 = fmaxf(Mx3, s3);
    }
#pragma unroll
    for (int m = 1; m < 16; m <<= 1) {
        Mx0 = fmaxf(Mx0, __shfl_xor(Mx0, m, 64));
        Mx1 = fmaxf(Mx1, __shfl_xor(Mx1, m, 64));
        Mx2 = fmaxf(Mx2, __shfl_xor(Mx2, m, 64));
        Mx3 = fmaxf(Mx3, __shfl_xor(Mx3, m, 64));
    }
    if (n16 == 0) {
        redM[kh2][rowDl + 0] = Mx0; redM[kh2][rowDl + 1] = Mx1;
        redM[kh2][rowDl + 2] = Mx2; redM[kh2][rowDl + 3] = Mx3;
    }
    __syncthreads();
    float Mg0 = fmaxf(redM[0][rowDl + 0], redM[1][rowDl + 0]);
    float Mg1 = fmaxf(redM[0][rowDl + 1], redM[1][rowDl + 1]);
    float Mg2 = fmaxf(redM[0][rowDl + 2], redM[1][rowDl + 2]);
    float Mg3 = fmaxf(redM[0][rowDl + 3], redM[1][rowDl + 3]);

    // ---- exp + row sum ----
    float S0 = 0.f, S1 = 0.f, S2 = 0.f, S3 = 0.f;
#pragma unroll
    for (int t = 0; t < 16; t++) {
        float e0 = __expf(acc[t][0] - Mg0);
        float e1 = __expf(acc[t][1] - Mg1);
        float e2 = __expf(acc[t][2] - Mg2);
        float e3 = __expf(acc[t][3] - Mg3);
        acc[t][0] = e0; acc[t][1] = e1; acc[t][2] = e2; acc[t][3] = e3;
        S0 += e0; S1 += e1; S2 += e2; S3 += e3;
    }
#pragma unroll
    for (int m = 1; m < 16; m <<= 1) {
        S0 += __shfl_xor(S0, m, 64); S1 += __shfl_xor(S1, m, 64);
        S2 += __shfl_xor(S2, m, 64); S3 += __shfl_xor(S3, m, 64);
    }
    if (n16 == 0) {
        redS[kh2][rowDl + 0] = S0; redS[kh2][rowDl + 1] = S1;
        redS[kh2][rowDl + 2] = S2; redS[kh2][rowDl + 3] = S3;
    }
    __syncthreads();
    const float i0 = Ac / (redS[0][rowDl + 0] + redS[1][rowDl + 0]);
    const float i1 = Ac / (redS[0][rowDl + 1] + redS[1][rowDl + 1]);
    const float i2 = Ac / (redS[0][rowDl + 2] + redS[1][rowDl + 2]);
    const float i3 = Ac / (redS[0][rowDl + 3] + redS[1][rowDl + 3]);

    // ---- store softmax part to P (bf16) ----
#pragma unroll
    for (int t = 0; t < 16; t++) {
        const int col = kbase + 16 * t + n16;
        Pl[(rowDl + 0) * PS + col] = bfbits(acc[t][0] * i0);
        Pl[(rowDl + 1) * PS + col] = bfbits(acc[t][1] * i1);
        Pl[(rowDl + 2) * PS + col] = bfbits(acc[t][2] * i2);
        Pl[(rowDl + 3) * PS + col] = bfbits(acc[t][3] * i3);
    }
    __syncthreads();

    // ---- blend with Ev + contiguous nontemporal prob write + P write-back ----
#pragma unroll
    for (int it = 0; it < 16; it++) {
        const int idx = it * 256 + tid;
        const int r = idx >> 7;
        const int c0 = (idx & 127) * 4;
        short* pp = &Pl[r * PS + c0];
        short4v pv = *(short4v*)pp;
        const short4v ev = *(const short4v*)(Evb + ((size_t)(b * cS + q0 + r)) * cS + c0);
        f32x4 o;
#pragma unroll
        for (int j = 0; j < 4; j++) o[j] = bff(pv[j]) + bff(ev[j]);
        __builtin_nontemporal_store(o, (f32x4*)(prob + (bh * cS + q0 + r) * cS + c0));
#pragma unroll
        for (int j = 0; j < 4; j++) pv[j] = bfbits(o[j]);
        *(short4v*)pp = pv;
    }
    __syncthreads();

    // ---- PV with precomputed bf16 V^T ----
    const int dhT = w & 1, qT = w >> 1;
    const int dhA = 16 * dhT + n16;
    const short* vtrow = VTb + (bh * cDH + dhA) * cS;
    f32x4 oacc = (f32x4){0.f, 0.f, 0.f, 0.f};
#pragma unroll
    for (int k0 = 0; k0 < cS; k0 += 32) {
        short8v av = *(const short8v*)(vtrow + k0 + quad * 8);
        short8v bv = *(short8v*)&Pl[(16 * qT + n16) * PS + k0 + quad * 8];
        oacc = __builtin_amdgcn_mfma_f32_16x16x32_bf16(av, bv, oacc, 0, 0, 0);
    }
    const int qg = q0 + 16 * qT + n16;
    const int dhD = 16 * dhT + quad * 4;
    float* op = out + ((size_t)b * cS + qg) * cD + h * cDH + dhD;
    __builtin_nontemporal_store(oacc, (f32x4*)op);
}

extern "C" void kernel_launch(void* const* d_in, const int* in_sizes, int n_in,
                              void* d_out, int out_size, void* d_ws, size_t ws_size,
                              hipStream_t stream) {
    const float* query = (const float*)d_in[0];
    const float* key   = (const float*)d_in[1];
    const float* value = (const float*)d_in[2];
    const float* rel   = (const float*)d_in[3];
    const float* tsp   = (const float*)d_in[4];
    const float* l1 = (const float*)d_in[6];
    const float* l2 = (const float*)d_in[7];
    const float* Wq = (const float*)d_in[8];
    const float* bq = (const float*)d_in[9];
    const float* Wk = (const float*)d_in[10];
    const float* bk = (const float*)d_in[11];
    const float* Wv = (const float*)d_in[12];
    const float* bv = (const float*)d_in[13];

    float* ws   = (float*)d_ws;
    short* Evb  = (short*)(ws + 3 * (size_t)cB * cS * cD);   // bf16, 8.4 MB
    float* out  = (float*)d_out;
    float* prob = out + (size_t)cB * cS * cD;

    proj_kernel<<<dim3(256, 3), 256, 0, stream>>>(query, key, value,
                                                  Wq, bq, Wk, bk, Wv, bv, ws);
    ev_kernel<<<dim3(2048), 256, 0, stream>>>(rel, tsp, l1, l2, Evb);
    attn2_kernel<<<dim3(16, 128), 256, 0, stream>>>(ws, Evb, l1, l2, out, prob);
}

// Round 10
// 289.359 us; speedup vs baseline: 1.4810x; 1.0255x over previous
//
#include <hip/hip_runtime.h>
#include <hip/hip_bf16.h>

static constexpr int cB  = 16;
static constexpr int cS  = 512;
static constexpr int cD  = 256;
static constexpr int cH  = 8;
static constexpr int cDH = 32;
static constexpr size_t cNE = (size_t)cB * cS * cD;   // elements per Q/K plane pair

typedef __attribute__((ext_vector_type(8))) short short8v;
typedef __attribute__((ext_vector_type(4))) short short4v;
typedef __attribute__((ext_vector_type(4))) float f32x4;

__device__ __forceinline__ short bfbits(float x) {
    __hip_bfloat16 h = __float2bfloat16(x);
    short s; __builtin_memcpy(&s, &h, 2); return s;
}
__device__ __forceinline__ float bff(short s) {
    __hip_bfloat16 h; __builtin_memcpy(&h, &s, 2); return __bfloat162float(h);
}

// ---------------------------------------------------------------------------
// Projection: C = X @ W^T + b via bf16 hi/lo MFMA (f32-grade accuracy).
// z=0 (Q), z=1 (K): output PRE-SPLIT bf16 hi/lo planes (same bytes as f32:
//   hi plane + lo plane; attn2 then loads MFMA fragments directly, no
//   per-block converts). z=2 (V): bf16 transposed VT[b][h][dh][k].
// ---------------------------------------------------------------------------
__global__ __launch_bounds__(256) void proj_kernel(
    const float* __restrict__ q_in, const float* __restrict__ k_in,
    const float* __restrict__ v_in,
    const float* __restrict__ Wq, const float* __restrict__ bq,
    const float* __restrict__ Wk, const float* __restrict__ bk,
    const float* __restrict__ Wv, const float* __restrict__ bv,
    float* __restrict__ ws)
{
    const int z = blockIdx.y;
    const float* X    = (z == 0) ? q_in : (z == 1) ? k_in : v_in;
    const float* W    = (z == 0) ? Wq   : (z == 1) ? Wk   : Wv;
    const float* bias = (z == 0) ? bq   : (z == 1) ? bk   : bv;
    short* HI  = (short*)ws + (size_t)z * 2 * cNE;    // z=0: Qhi, z=1: Khi
    short* LO  = HI + cNE;
    short* VTb = (short*)(ws + 2 * cNE);

    const int tid  = threadIdx.x;
    const int w    = tid >> 6;
    const int lane = tid & 63;
    const int n16  = lane & 15;
    const int quad = lane >> 4;

    const int i0 = blockIdx.x * 32 + 16 * (w & 1);
    const int j0 = 128 * (w >> 1);

    const float* xrow = X + (size_t)(i0 + n16) * cD + quad * 8;
    short8v a_hi[8], a_lo[8];
#pragma unroll
    for (int c = 0; c < 8; c++) {
        float xa[8];
        *(float4*)&xa[0] = *(const float4*)(xrow + c * 32);
        *(float4*)&xa[4] = *(const float4*)(xrow + c * 32 + 4);
#pragma unroll
        for (int j = 0; j < 8; j++) {
            short hb = bfbits(xa[j]);
            a_hi[c][j] = hb;
            a_lo[c][j] = bfbits(xa[j] - bff(hb));
        }
    }

#pragma unroll
    for (int t = 0; t < 8; t++) {
        const int jb = j0 + t * 16;
        const float* wrow = W + (size_t)(jb + n16) * cD + quad * 8;
        f32x4 acc = (f32x4){0.f, 0.f, 0.f, 0.f};
#pragma unroll
        for (int c = 0; c < 8; c++) {
            float wv_[8];
            *(float4*)&wv_[0] = *(const float4*)(wrow + c * 32);
            *(float4*)&wv_[4] = *(const float4*)(wrow + c * 32 + 4);
            short8v b_hi, b_lo;
#pragma unroll
            for (int j = 0; j < 8; j++) {
                short hb = bfbits(wv_[j]);
                b_hi[j] = hb;
                b_lo[j] = bfbits(wv_[j] - bff(hb));
            }
            acc = __builtin_amdgcn_mfma_f32_16x16x32_bf16(a_hi[c], b_hi, acc, 0, 0, 0);
            acc = __builtin_amdgcn_mfma_f32_16x16x32_bf16(a_hi[c], b_lo, acc, 0, 0, 0);
            acc = __builtin_amdgcn_mfma_f32_16x16x32_bf16(a_lo[c], b_hi, acc, 0, 0, 0);
        }
        const int jg = jb + n16;
        const float bv_ = bias[jg];
        const int h_ = jg >> 5, dh = jg & 31;
        if (z == 2) {
#pragma unroll
            for (int r = 0; r < 4; r++) {
                int gi = i0 + quad * 4 + r;
                int b_ = gi >> 9, s_ = gi & 511;
                VTb[(((size_t)(b_ * cH + h_)) * cDH + dh) * cS + s_] =
                    bfbits(acc[r] + bv_);
            }
        } else {
#pragma unroll
            for (int r = 0; r < 4; r++) {
                int gi = i0 + quad * 4 + r;
                int b_ = gi >> 9, s_ = gi & 511;
                size_t idx = (((size_t)(b_ * cH + h_)) * cS + s_) * cDH + dh;
                float v = acc[r] + bv_;
                short hb2 = bfbits(v);
                HI[idx] = hb2;
                LO[idx] = bfbits(v - bff(hb2));
            }
        }
    }
}

// ---------------------------------------------------------------------------
// Ev kernel: Ev[b][q][k] = Bc*time_attn + Cc*rel_attn (head-independent),
// bf16. One wave per (b,q) row. Triangular predicated loads.
// ---------------------------------------------------------------------------
__global__ __launch_bounds__(256) void ev_kernel(
    const float* __restrict__ rel, const float* __restrict__ ts,
    const float* __restrict__ l1p, const float* __restrict__ l2p,
    short* __restrict__ Evb)
{
    const int w = threadIdx.x >> 6, lane = threadIdx.x & 63;
    const int row = blockIdx.x * 4 + w;
    const int q = row & 511;
    const float* tr = ts  + (size_t)row * cS;
    const float* rr = rel + (size_t)row * cS;
    const float l1 = l1p[0], l2 = l2p[0];
    const float Bc = (1.f - l1) * l2;
    const float Cc = l1;

    float tv[8], rv[8];
    float tmax = -1e30f, rmax = -1e30f;
#pragma unroll
    for (int j = 0; j < 8; j++) {
        int k = lane + 64 * j;
        float tl_ = (k <= q) ? tr[k] : 0.f;
        float r   = (k >  q) ? rr[k] : 0.f;
        tv[j] = (k <= q) ? __expf(-fabsf(tl_)) : -1e30f;
        rv[j] = (k > q && r != 0.f) ? r : -10000.f;
        tmax = fmaxf(tmax, tv[j]);
        rmax = fmaxf(rmax, rv[j]);
    }
#pragma unroll
    for (int m = 1; m < 64; m <<= 1) {
        tmax = fmaxf(tmax, __shfl_xor(tmax, m, 64));
        rmax = fmaxf(rmax, __shfl_xor(rmax, m, 64));
    }
    float te[8], re[8];
    float tsum = 0.f, rsum = 0.f;
#pragma unroll
    for (int j = 0; j < 8; j++) {
        te[j] = (tv[j] > -1e29f) ? __expf(tv[j] - tmax) : 0.f;
        re[j] = __expf(rv[j] - rmax);
        tsum += te[j]; rsum += re[j];
    }
#pragma unroll
    for (int m = 1; m < 64; m <<= 1) {
        tsum += __shfl_xor(tsum, m, 64);
        rsum += __shfl_xor(rsum, m, 64);
    }
    const float ti = Bc / tsum, ri = Cc / rsum;
#pragma unroll
    for (int j = 0; j < 8; j++) {
        int k = lane + 64 * j;
        Evb[(size_t)row * cS + k] = bfbits(te[j] * ti + re[j] * ri);
    }
}

// ---------------------------------------------------------------------------
// Attention v7 (fused): acc statically indexed (registers, round-9 fix);
// Q/K fragments now loaded directly from proj's pre-split bf16 hi/lo planes
// — two 16B loads per K tile replace f32 loads + ~48 VALU convert ops.
// ---------------------------------------------------------------------------
__global__ __launch_bounds__(256, 4) void attn2_kernel(
    const float* __restrict__ ws, const short* __restrict__ Evb,
    const float* __restrict__ l1p, const float* __restrict__ l2p,
    float* __restrict__ out, float* __restrict__ prob)
{
    constexpr int PS = 536;
    __shared__ short Pl[32 * PS];
    __shared__ float redM[2][32];
    __shared__ float redS[2][32];

    const int tid  = threadIdx.x;
    const int w    = tid >> 6;
    const int lane = tid & 63;
    const int n16  = lane & 15;
    const int quad = lane >> 4;

    // XCD-aware remap: all 128 blocks of batch b land on XCD b%8.
    const int flat = blockIdx.y * gridDim.x + blockIdx.x;
    const int xcd  = flat & 7;
    const int slot = flat >> 3;
    const int b  = xcd + 8 * (slot >> 7);
    const int h  = (slot >> 4) & 7;
    const int qt = slot & 15;
    const size_t bh = (size_t)b * cH + h;
    const int q0 = qt * 32;

    const short* Qhi = (const short*)ws;
    const short* Qlo = Qhi + cNE;
    const short* Khi = Qhi + 2 * cNE;
    const short* Klo = Qhi + 3 * cNE;
    const short* VTb = (const short*)(ws + 2 * cNE);

    const float l1 = l1p[0], l2 = l2p[0];
    const float Ac = (1.f - l1) * (1.f - l2);

    const int qhH = w & 1;
    const int kh2 = w >> 1;
    const int kbase = 256 * kh2;

    // ---- A fragment: pre-split Q hi/lo, two 16B loads ----
    const int rowA = q0 + 16 * qhH + n16;
    const size_t qoff = (bh * cS + rowA) * cDH + quad * 8;
    short8v a_hi = *(const short8v*)(Qhi + qoff);
    short8v a_lo = *(const short8v*)(Qlo + qoff);

    // ---- QK^T: 16 key tiles, statically unrolled, uniform skip ----
    const int tl = (kbase <= q0 + 31) ? min(15, (q0 + 31 - kbase) >> 4) : -1;
    f32x4 acc[16];
#pragma unroll
    for (int t = 0; t < 16; t++) {
        acc[t] = (f32x4){0.f, 0.f, 0.f, 0.f};
        if (t <= tl) {
            const size_t koff = (bh * cS + kbase + 16 * t + n16) * cDH + quad * 8;
            short8v b_hi = *(const short8v*)(Khi + koff);
            short8v b_lo = *(const short8v*)(Klo + koff);
            acc[t] = __builtin_amdgcn_mfma_f32_16x16x32_bf16(a_hi, b_hi, acc[t], 0, 0, 0);
            acc[t] = __builtin_amdgcn_mfma_f32_16x16x32_bf16(a_hi, b_lo, acc[t], 0, 0, 0);
            acc[t] = __builtin_amdgcn_mfma_f32_16x16x32_bf16(a_lo, b_hi, acc[t], 0, 0, 0);
        }
    }

    // ---- mask + scale + row max ----
    const float scale = 0.17677669529663687f;
    const int rowDl = 16 * qhH + quad * 4;
    float Mx0 = -1e30f, Mx1 = -1e30f, Mx2 = -1e30f, Mx3 = -1e30f;
#pragma unroll
    for (int t = 0; t < 16; t++) {
        const int kg = kbase + 16 * t + n16;
        const int rg = q0 + rowDl;
        float s0 = (kg <= rg + 0) ? acc[t][0] * scale : -1e30f;
        float s1 = (kg <= rg + 1) ? acc[t][1] * scale : -1e30f;
        float s2 = (kg <= rg + 2) ? acc[t][2] * scale : -1e30f;
        float s3 = (kg <= rg + 3) ? acc[t][3] * scale : -1e30f;
        acc[t][0] = s0; acc[t][1] = s1; acc[t][2] = s2; acc[t][3] = s3;
        Mx0 = fmaxf(Mx0, s0); Mx1 = fmaxf(Mx1, s1);
        Mx2 = fmaxf(Mx2, s2); Mx3 = fmaxf(Mx3, s3);
    }
#pragma unroll
    for (int m = 1; m < 16; m <<= 1) {
        Mx0 = fmaxf(Mx0, __shfl_xor(Mx0, m, 64));
        Mx1 = fmaxf(Mx1, __shfl_xor(Mx1, m, 64));
        Mx2 = fmaxf(Mx2, __shfl_xor(Mx2, m, 64));
        Mx3 = fmaxf(Mx3, __shfl_xor(Mx3, m, 64));
    }
    if (n16 == 0) {
        redM[kh2][rowDl + 0] = Mx0; redM[kh2][rowDl + 1] = Mx1;
        redM[kh2][rowDl + 2] = Mx2; redM[kh2][rowDl + 3] = Mx3;
    }
    __syncthreads();
    float Mg0 = fmaxf(redM[0][rowDl + 0], redM[1][rowDl + 0]);
    float Mg1 = fmaxf(redM[0][rowDl + 1], redM[1][rowDl + 1]);
    float Mg2 = fmaxf(redM[0][rowDl + 2], redM[1][rowDl + 2]);
    float Mg3 = fmaxf(redM[0][rowDl + 3], redM[1][rowDl + 3]);

    // ---- exp + row sum ----
    float S0 = 0.f, S1 = 0.f, S2 = 0.f, S3 = 0.f;
#pragma unroll
    for (int t = 0; t < 16; t++) {
        float e0 = __expf(acc[t][0] - Mg0);
        float e1 = __expf(acc[t][1] - Mg1);
        float e2 = __expf(acc[t][2] - Mg2);
        float e3 = __expf(acc[t][3] - Mg3);
        acc[t][0] = e0; acc[t][1] = e1; acc[t][2] = e2; acc[t][3] = e3;
        S0 += e0; S1 += e1; S2 += e2; S3 += e3;
    }
#pragma unroll
    for (int m = 1; m < 16; m <<= 1) {
        S0 += __shfl_xor(S0, m, 64); S1 += __shfl_xor(S1, m, 64);
        S2 += __shfl_xor(S2, m, 64); S3 += __shfl_xor(S3, m, 64);
    }
    if (n16 == 0) {
        redS[kh2][rowDl + 0] = S0; redS[kh2][rowDl + 1] = S1;
        redS[kh2][rowDl + 2] = S2; redS[kh2][rowDl + 3] = S3;
    }
    __syncthreads();
    const float i0 = Ac / (redS[0][rowDl + 0] + redS[1][rowDl + 0]);
    const float i1 = Ac / (redS[0][rowDl + 1] + redS[1][rowDl + 1]);
    const float i2 = Ac / (redS[0][rowDl + 2] + redS[1][rowDl + 2]);
    const float i3 = Ac / (redS[0][rowDl + 3] + redS[1][rowDl + 3]);

    // ---- store softmax part to P (bf16) ----
#pragma unroll
    for (int t = 0; t < 16; t++) {
        const int col = kbase + 16 * t + n16;
        Pl[(rowDl + 0) * PS + col] = bfbits(acc[t][0] * i0);
        Pl[(rowDl + 1) * PS + col] = bfbits(acc[t][1] * i1);
        Pl[(rowDl + 2) * PS + col] = bfbits(acc[t][2] * i2);
        Pl[(rowDl + 3) * PS + col] = bfbits(acc[t][3] * i3);
    }
    __syncthreads();

    // ---- blend with Ev + contiguous nontemporal prob write + P write-back ----
#pragma unroll
    for (int it = 0; it < 16; it++) {
        const int idx = it * 256 + tid;
        const int r = idx >> 7;
        const int c0 = (idx & 127) * 4;
        short* pp = &Pl[r * PS + c0];
        short4v pv = *(short4v*)pp;
        const short4v ev = *(const short4v*)(Evb + ((size_t)(b * cS + q0 + r)) * cS + c0);
        f32x4 o;
#pragma unroll
        for (int j = 0; j < 4; j++) o[j] = bff(pv[j]) + bff(ev[j]);
        __builtin_nontemporal_store(o, (f32x4*)(prob + (bh * cS + q0 + r) * cS + c0));
#pragma unroll
        for (int j = 0; j < 4; j++) pv[j] = bfbits(o[j]);
        *(short4v*)pp = pv;
    }
    __syncthreads();

    // ---- PV with precomputed bf16 V^T ----
    const int dhT = w & 1, qT = w >> 1;
    const int dhA = 16 * dhT + n16;
    const short* vtrow = VTb + (bh * cDH + dhA) * cS;
    f32x4 oacc = (f32x4){0.f, 0.f, 0.f, 0.f};
#pragma unroll
    for (int k0 = 0; k0 < cS; k0 += 32) {
        short8v av = *(const short8v*)(vtrow + k0 + quad * 8);
        short8v bv = *(short8v*)&Pl[(16 * qT + n16) * PS + k0 + quad * 8];
        oacc = __builtin_amdgcn_mfma_f32_16x16x32_bf16(av, bv, oacc, 0, 0, 0);
    }
    const int qg = q0 + 16 * qT + n16;
    const int dhD = 16 * dhT + quad * 4;
    float* op = out + ((size_t)b * cS + qg) * cD + h * cDH + dhD;
    __builtin_nontemporal_store(oacc, (f32x4*)op);
}

extern "C" void kernel_launch(void* const* d_in, const int* in_sizes, int n_in,
                              void* d_out, int out_size, void* d_ws, size_t ws_size,
                              hipStream_t stream) {
    const float* query = (const float*)d_in[0];
    const float* key   = (const float*)d_in[1];
    const float* value = (const float*)d_in[2];
    const float* rel   = (const float*)d_in[3];
    const float* tsp   = (const float*)d_in[4];
    const float* l1 = (const float*)d_in[6];
    const float* l2 = (const float*)d_in[7];
    const float* Wq = (const float*)d_in[8];
    const float* bq = (const float*)d_in[9];
    const float* Wk = (const float*)d_in[10];
    const float* bk = (const float*)d_in[11];
    const float* Wv = (const float*)d_in[12];
    const float* bv = (const float*)d_in[13];

    float* ws   = (float*)d_ws;
    short* Evb  = (short*)(ws + 3 * cNE);   // bf16, 8.4 MB
    float* out  = (float*)d_out;
    float* prob = out + cNE;

    proj_kernel<<<dim3(256, 3), 256, 0, stream>>>(query, key, value,
                                                  Wq, bq, Wk, bk, Wv, bv, ws);
    ev_kernel<<<dim3(2048), 256, 0, stream>>>(rel, tsp, l1, l2, Evb);
    attn2_kernel<<<dim3(16, 128), 256, 0, stream>>>(ws, Evb, l1, l2, out, prob);
}

// Round 11
// 283.221 us; speedup vs baseline: 1.5131x; 1.0217x over previous
//
#include <hip/hip_runtime.h>
#include <hip/hip_bf16.h>

static constexpr int cB  = 16;
static constexpr int cS  = 512;
static constexpr int cD  = 256;
static constexpr int cH  = 8;
static constexpr int cDH = 32;
static constexpr size_t cNE = (size_t)cB * cS * cD;   // elements per Q/K plane pair
static constexpr size_t cWN = (size_t)cD * cD;        // 65536 elems per W

typedef __attribute__((ext_vector_type(8))) short short8v;
typedef __attribute__((ext_vector_type(4))) short short4v;
typedef __attribute__((ext_vector_type(4))) float f32x4;

__device__ __forceinline__ short bfbits(float x) {
    __hip_bfloat16 h = __float2bfloat16(x);
    short s; __builtin_memcpy(&s, &h, 2); return s;
}
__device__ __forceinline__ float bff(short s) {
    __hip_bfloat16 h; __builtin_memcpy(&h, &s, 2); return __bfloat162float(h);
}

// ---------------------------------------------------------------------------
// W split kernel: pre-split Wq/Wk/Wv into bf16 hi/lo planes ONCE.
// Previously every one of 256 proj blocks per z re-converted the same W
// (~3000 VALU ops/thread -> proj was VALU-bound on redundant conversion).
// ---------------------------------------------------------------------------
__global__ __launch_bounds__(256) void wsplit_kernel(
    const float* __restrict__ Wq, const float* __restrict__ Wk,
    const float* __restrict__ Wv, short* __restrict__ Wsp)
{
    const int z = blockIdx.y;
    const float* W = (z == 0) ? Wq : (z == 1) ? Wk : Wv;
    short* hi = Wsp + (size_t)z * 2 * cWN;
    short* lo = hi + cWN;
    const int i = (blockIdx.x * 256 + threadIdx.x) * 4;
    float4 v = *(const float4*)(W + i);
    float va[4] = {v.x, v.y, v.z, v.w};
    short4v h, l;
#pragma unroll
    for (int j = 0; j < 4; j++) {
        short hb = bfbits(va[j]);
        h[j] = hb;
        l[j] = bfbits(va[j] - bff(hb));
    }
    *(short4v*)(hi + i) = h;
    *(short4v*)(lo + i) = l;
}

// ---------------------------------------------------------------------------
// prep kernel: fused projection + Ev in ONE dispatch so the memory-bound Ev
// blocks stream concurrently with proj's MFMA blocks (same-stream kernels
// never overlap; hipEvent* is forbidden, so fusion is the only concurrency).
//   blocks [0,768):   proj role. z = bid>>8. z=0 (Q), z=1 (K): pre-split
//                     bf16 hi/lo planes. z=2 (V): bf16 transposed VT.
//                     W fragments come PRE-SPLIT from wsplit_kernel.
//   blocks [768,2816): ev role, Ev[b][q][k] = Bc*time_attn + Cc*rel_attn.
// ---------------------------------------------------------------------------
__global__ __launch_bounds__(256) void prep_kernel(
    const float* __restrict__ q_in, const float* __restrict__ k_in,
    const float* __restrict__ v_in, const short* __restrict__ Wsp,
    const float* __restrict__ bq, const float* __restrict__ bk,
    const float* __restrict__ bv,
    const float* __restrict__ rel, const float* __restrict__ ts,
    const float* __restrict__ l1p, const float* __restrict__ l2p,
    float* __restrict__ ws, short* __restrict__ Evb)
{
    const int bid = blockIdx.x;
    const int tid = threadIdx.x;
    const int w    = tid >> 6;
    const int lane = tid & 63;

    if (bid < 768) {
        // ================= proj role =================
        const int z  = bid >> 8;
        const int bx = bid & 255;
        const float* X    = (z == 0) ? q_in : (z == 1) ? k_in : v_in;
        const float* bias = (z == 0) ? bq   : (z == 1) ? bk   : bv;
        const short* Whi = Wsp + (size_t)z * 2 * cWN;
        const short* Wlo = Whi + cWN;
        short* HI  = (short*)ws + (size_t)z * 2 * cNE;
        short* LO  = HI + cNE;
        short* VTb = (short*)(ws + 2 * cNE);

        const int n16  = lane & 15;
        const int quad = lane >> 4;
        const int i0 = bx * 32 + 16 * (w & 1);
        const int j0 = 128 * (w >> 1);

        // A fragments: X rows, full K=256, bf16 hi/lo (unique per block).
        const float* xrow = X + (size_t)(i0 + n16) * cD + quad * 8;
        short8v a_hi[8], a_lo[8];
#pragma unroll
        for (int c = 0; c < 8; c++) {
            float xa[8];
            *(float4*)&xa[0] = *(const float4*)(xrow + c * 32);
            *(float4*)&xa[4] = *(const float4*)(xrow + c * 32 + 4);
#pragma unroll
            for (int j = 0; j < 8; j++) {
                short hb = bfbits(xa[j]);
                a_hi[c][j] = hb;
                a_lo[c][j] = bfbits(xa[j] - bff(hb));
            }
        }

#pragma unroll
        for (int t = 0; t < 8; t++) {
            const int jb = j0 + t * 16;
            const size_t wbase = (size_t)(jb + n16) * cD + quad * 8;
            f32x4 acc = (f32x4){0.f, 0.f, 0.f, 0.f};
#pragma unroll
            for (int c = 0; c < 8; c++) {
                short8v b_hi = *(const short8v*)(Whi + wbase + c * 32);
                short8v b_lo = *(const short8v*)(Wlo + wbase + c * 32);
                acc = __builtin_amdgcn_mfma_f32_16x16x32_bf16(a_hi[c], b_hi, acc, 0, 0, 0);
                acc = __builtin_amdgcn_mfma_f32_16x16x32_bf16(a_hi[c], b_lo, acc, 0, 0, 0);
                acc = __builtin_amdgcn_mfma_f32_16x16x32_bf16(a_lo[c], b_hi, acc, 0, 0, 0);
            }
            const int jg = jb + n16;
            const float bv_ = bias[jg];
            const int h_ = jg >> 5, dh = jg & 31;
            if (z == 2) {
#pragma unroll
                for (int r = 0; r < 4; r++) {
                    int gi = i0 + quad * 4 + r;
                    int b_ = gi >> 9, s_ = gi & 511;
                    VTb[(((size_t)(b_ * cH + h_)) * cDH + dh) * cS + s_] =
                        bfbits(acc[r] + bv_);
                }
            } else {
#pragma unroll
                for (int r = 0; r < 4; r++) {
                    int gi = i0 + quad * 4 + r;
                    int b_ = gi >> 9, s_ = gi & 511;
                    size_t idx = (((size_t)(b_ * cH + h_)) * cS + s_) * cDH + dh;
                    float v = acc[r] + bv_;
                    short hb2 = bfbits(v);
                    HI[idx] = hb2;
                    LO[idx] = bfbits(v - bff(hb2));
                }
            }
        }
    } else {
        // ================= ev role =================
        const int row = (bid - 768) * 4 + w;          // b*512 + q
        const int q = row & 511;
        const float* tr = ts  + (size_t)row * cS;
        const float* rr = rel + (size_t)row * cS;
        const float l1 = l1p[0], l2 = l2p[0];
        const float Bc = (1.f - l1) * l2;
        const float Cc = l1;

        float tv[8], rv[8];
        float tmax = -1e30f, rmax = -1e30f;
#pragma unroll
        for (int j = 0; j < 8; j++) {
            int k = lane + 64 * j;
            float tl_ = (k <= q) ? tr[k] : 0.f;
            float r   = (k >  q) ? rr[k] : 0.f;
            tv[j] = (k <= q) ? __expf(-fabsf(tl_)) : -1e30f;
            rv[j] = (k > q && r != 0.f) ? r : -10000.f;
            tmax = fmaxf(tmax, tv[j]);
            rmax = fmaxf(rmax, rv[j]);
        }
#pragma unroll
        for (int m = 1; m < 64; m <<= 1) {
            tmax = fmaxf(tmax, __shfl_xor(tmax, m, 64));
            rmax = fmaxf(rmax, __shfl_xor(rmax, m, 64));
        }
        float te[8], re[8];
        float tsum = 0.f, rsum = 0.f;
#pragma unroll
        for (int j = 0; j < 8; j++) {
            te[j] = (tv[j] > -1e29f) ? __expf(tv[j] - tmax) : 0.f;
            re[j] = __expf(rv[j] - rmax);
            tsum += te[j]; rsum += re[j];
        }
#pragma unroll
        for (int m = 1; m < 64; m <<= 1) {
            tsum += __shfl_xor(tsum, m, 64);
            rsum += __shfl_xor(rsum, m, 64);
        }
        const float ti = Bc / tsum, ri = Cc / rsum;
#pragma unroll
        for (int j = 0; j < 8; j++) {
            int k = lane + 64 * j;
            Evb[(size_t)row * cS + k] = bfbits(te[j] * ti + re[j] * ri);
        }
    }
}

// ---------------------------------------------------------------------------
// Attention (fused): acc statically indexed (registers); Q/K fragments
// loaded directly from pre-split bf16 hi/lo planes; XCD-aware remap;
// nontemporal prob/out stores. Unchanged from round 10.
// ---------------------------------------------------------------------------
__global__ __launch_bounds__(256, 4) void attn2_kernel(
    const float* __restrict__ ws, const short* __restrict__ Evb,
    const float* __restrict__ l1p, const float* __restrict__ l2p,
    float* __restrict__ out, float* __restrict__ prob)
{
    constexpr int PS = 536;
    __shared__ short Pl[32 * PS];
    __shared__ float redM[2][32];
    __shared__ float redS[2][32];

    const int tid  = threadIdx.x;
    const int w    = tid >> 6;
    const int lane = tid & 63;
    const int n16  = lane & 15;
    const int quad = lane >> 4;

    const int flat = blockIdx.y * gridDim.x + blockIdx.x;
    const int xcd  = flat & 7;
    const int slot = flat >> 3;
    const int b  = xcd + 8 * (slot >> 7);
    const int h  = (slot >> 4) & 7;
    const int qt = slot & 15;
    const size_t bh = (size_t)b * cH + h;
    const int q0 = qt * 32;

    const short* Qhi = (const short*)ws;
    const short* Qlo = Qhi + cNE;
    const short* Khi = Qhi + 2 * cNE;
    const short* Klo = Qhi + 3 * cNE;
    const short* VTb = (const short*)(ws + 2 * cNE);

    const float l1 = l1p[0], l2 = l2p[0];
    const float Ac = (1.f - l1) * (1.f - l2);

    const int qhH = w & 1;
    const int kh2 = w >> 1;
    const int kbase = 256 * kh2;

    const int rowA = q0 + 16 * qhH + n16;
    const size_t qoff = (bh * cS + rowA) * cDH + quad * 8;
    short8v a_hi = *(const short8v*)(Qhi + qoff);
    short8v a_lo = *(const short8v*)(Qlo + qoff);

    const int tl = (kbase <= q0 + 31) ? min(15, (q0 + 31 - kbase) >> 4) : -1;
    f32x4 acc[16];
#pragma unroll
    for (int t = 0; t < 16; t++) {
        acc[t] = (f32x4){0.f, 0.f, 0.f, 0.f};
        if (t <= tl) {
            const size_t koff = (bh * cS + kbase + 16 * t + n16) * cDH + quad * 8;
            short8v b_hi = *(const short8v*)(Khi + koff);
            short8v b_lo = *(const short8v*)(Klo + koff);
            acc[t] = __builtin_amdgcn_mfma_f32_16x16x32_bf16(a_hi, b_hi, acc[t], 0, 0, 0);
            acc[t] = __builtin_amdgcn_mfma_f32_16x16x32_bf16(a_hi, b_lo, acc[t], 0, 0, 0);
            acc[t] = __builtin_amdgcn_mfma_f32_16x16x32_bf16(a_lo, b_hi, acc[t], 0, 0, 0);
        }
    }

    const float scale = 0.17677669529663687f;
    const int rowDl = 16 * qhH + quad * 4;
    float Mx0 = -1e30f, Mx1 = -1e30f, Mx2 = -1e30f, Mx3 = -1e30f;
#pragma unroll
    for (int t = 0; t < 16; t++) {
        const int kg = kbase + 16 * t + n16;
        const int rg = q0 + rowDl;
        float s0 = (kg <= rg + 0) ? acc[t][0] * scale : -1e30f;
        float s1 = (kg <= rg + 1) ? acc[t][1] * scale : -1e30f;
        float s2 = (kg <= rg + 2) ? acc[t][2] * scale : -1e30f;
        float s3 = (kg <= rg + 3) ? acc[t][3] * scale : -1e30f;
        acc[t][0] = s0; acc[t][1] = s1; acc[t][2] = s2; acc[t][3] = s3;
        Mx0 = fmaxf(Mx0, s0); Mx1 = fmaxf(Mx1, s1);
        Mx2 = fmaxf(Mx2, s2); Mx3 = fmaxf(Mx3, s3);
    }
#pragma unroll
    for (int m = 1; m < 16; m <<= 1) {
        Mx0 = fmaxf(Mx0, __shfl_xor(Mx0, m, 64));
        Mx1 = fmaxf(Mx1, __shfl_xor(Mx1, m, 64));
        Mx2 = fmaxf(Mx2, __shfl_xor(Mx2, m, 64));
        Mx3 = fmaxf(Mx3, __shfl_xor(Mx3, m, 64));
    }
    if (n16 == 0) {
        redM[kh2][rowDl + 0] = Mx0; redM[kh2][rowDl + 1] = Mx1;
        redM[kh2][rowDl + 2] = Mx2; redM[kh2][rowDl + 3] = Mx3;
    }
    __syncthreads();
    float Mg0 = fmaxf(redM[0][rowDl + 0], redM[1][rowDl + 0]);
    float Mg1 = fmaxf(redM[0][rowDl + 1], redM[1][rowDl + 1]);
    float Mg2 = fmaxf(redM[0][rowDl + 2], redM[1][rowDl + 2]);
    float Mg3 = fmaxf(redM[0][rowDl + 3], redM[1][rowDl + 3]);

    float S0 = 0.f, S1 = 0.f, S2 = 0.f, S3 = 0.f;
#pragma unroll
    for (int t = 0; t < 16; t++) {
        float e0 = __expf(acc[t][0] - Mg0);
        float e1 = __expf(acc[t][1] - Mg1);
        float e2 = __expf(acc[t][2] - Mg2);
        float e3 = __expf(acc[t][3] - Mg3);
        acc[t][0] = e0; acc[t][1] = e1; acc[t][2] = e2; acc[t][3] = e3;
        S0 += e0; S1 += e1; S2 += e2; S3 += e3;
    }
#pragma unroll
    for (int m = 1; m < 16; m <<= 1) {
        S0 += __shfl_xor(S0, m, 64); S1 += __shfl_xor(S1, m, 64);
        S2 += __shfl_xor(S2, m, 64); S3 += __shfl_xor(S3, m, 64);
    }
    if (n16 == 0) {
        redS[kh2][rowDl + 0] = S0; redS[kh2][rowDl + 1] = S1;
        redS[kh2][rowDl + 2] = S2; redS[kh2][rowDl + 3] = S3;
    }
    __syncthreads();
    const float i0 = Ac / (redS[0][rowDl + 0] + redS[1][rowDl + 0]);
    const float i1 = Ac / (redS[0][rowDl + 1] + redS[1][rowDl + 1]);
    const float i2 = Ac / (redS[0][rowDl + 2] + redS[1][rowDl + 2]);
    const float i3 = Ac / (redS[0][rowDl + 3] + redS[1][rowDl + 3]);

#pragma unroll
    for (int t = 0; t < 16; t++) {
        const int col = kbase + 16 * t + n16;
        Pl[(rowDl + 0) * PS + col] = bfbits(acc[t][0] * i0);
        Pl[(rowDl + 1) * PS + col] = bfbits(acc[t][1] * i1);
        Pl[(rowDl + 2) * PS + col] = bfbits(acc[t][2] * i2);
        Pl[(rowDl + 3) * PS + col] = bfbits(acc[t][3] * i3);
    }
    __syncthreads();

#pragma unroll
    for (int it = 0; it < 16; it++) {
        const int idx = it * 256 + tid;
        const int r = idx >> 7;
        const int c0 = (idx & 127) * 4;
        short* pp = &Pl[r * PS + c0];
        short4v pv = *(short4v*)pp;
        const short4v ev = *(const short4v*)(Evb + ((size_t)(b * cS + q0 + r)) * cS + c0);
        f32x4 o;
#pragma unroll
        for (int j = 0; j < 4; j++) o[j] = bff(pv[j]) + bff(ev[j]);
        __builtin_nontemporal_store(o, (f32x4*)(prob + (bh * cS + q0 + r) * cS + c0));
#pragma unroll
        for (int j = 0; j < 4; j++) pv[j] = bfbits(o[j]);
        *(short4v*)pp = pv;
    }
    __syncthreads();

    const int dhT = w & 1, qT = w >> 1;
    const int dhA = 16 * dhT + n16;
    const short* vtrow = VTb + (bh * cDH + dhA) * cS;
    f32x4 oacc = (f32x4){0.f, 0.f, 0.f, 0.f};
#pragma unroll
    for (int k0 = 0; k0 < cS; k0 += 32) {
        short8v av = *(const short8v*)(vtrow + k0 + quad * 8);
        short8v bv = *(short8v*)&Pl[(16 * qT + n16) * PS + k0 + quad * 8];
        oacc = __builtin_amdgcn_mfma_f32_16x16x32_bf16(av, bv, oacc, 0, 0, 0);
    }
    const int qg = q0 + 16 * qT + n16;
    const int dhD = 16 * dhT + quad * 4;
    float* op = out + ((size_t)b * cS + qg) * cD + h * cDH + dhD;
    __builtin_nontemporal_store(oacc, (f32x4*)op);
}

extern "C" void kernel_launch(void* const* d_in, const int* in_sizes, int n_in,
                              void* d_out, int out_size, void* d_ws, size_t ws_size,
                              hipStream_t stream) {
    const float* query = (const float*)d_in[0];
    const float* key   = (const float*)d_in[1];
    const float* value = (const float*)d_in[2];
    const float* rel   = (const float*)d_in[3];
    const float* tsp   = (const float*)d_in[4];
    const float* l1 = (const float*)d_in[6];
    const float* l2 = (const float*)d_in[7];
    const float* Wq = (const float*)d_in[8];
    const float* bq = (const float*)d_in[9];
    const float* Wk = (const float*)d_in[10];
    const float* bk = (const float*)d_in[11];
    const float* Wv = (const float*)d_in[12];
    const float* bv = (const float*)d_in[13];

    float* ws   = (float*)d_ws;
    short* Evb  = (short*)(ws + 3 * cNE);                 // bf16, 8.4 MB
    short* Wsp  = Evb + (size_t)cB * cS * cS;             // bf16 hi/lo W, 786 KB
    float* out  = (float*)d_out;
    float* prob = out + cNE;

    wsplit_kernel<<<dim3(64, 3), 256, 0, stream>>>(Wq, Wk, Wv, Wsp);
    prep_kernel<<<dim3(2816), 256, 0, stream>>>(query, key, value, Wsp,
                                                bq, bk, bv, rel, tsp,
                                                l1, l2, ws, Evb);
    attn2_kernel<<<dim3(16, 128), 256, 0, stream>>>(ws, Evb, l1, l2, out, prob);
}

// Round 13
// 281.396 us; speedup vs baseline: 1.5229x; 1.0065x over previous
//
#include <hip/hip_runtime.h>
#include <hip/hip_bf16.h>

static constexpr int cB  = 16;
static constexpr int cS  = 512;
static constexpr int cD  = 256;
static constexpr int cH  = 8;
static constexpr int cDH = 32;
static constexpr size_t cNE = (size_t)cB * cS * cD;   // elements per Q/K plane pair
static constexpr size_t cWN = (size_t)cD * cD;        // 65536 elems per W

typedef __attribute__((ext_vector_type(8))) short short8v;
typedef __attribute__((ext_vector_type(4))) short short4v;
typedef __attribute__((ext_vector_type(4))) float f32x4;

__device__ __forceinline__ short bfbits(float x) {
    __hip_bfloat16 h = __float2bfloat16(x);
    short s; __builtin_memcpy(&s, &h, 2); return s;
}
__device__ __forceinline__ float bff(short s) {
    __hip_bfloat16 h; __builtin_memcpy(&h, &s, 2); return __bfloat162float(h);
}

// ---------------------------------------------------------------------------
// W split kernel: pre-split Wq/Wk/Wv into bf16 hi/lo planes ONCE.
// ---------------------------------------------------------------------------
__global__ __launch_bounds__(256) void wsplit_kernel(
    const float* __restrict__ Wq, const float* __restrict__ Wk,
    const float* __restrict__ Wv, short* __restrict__ Wsp)
{
    const int z = blockIdx.y;
    const float* W = (z == 0) ? Wq : (z == 1) ? Wk : Wv;
    short* hi = Wsp + (size_t)z * 2 * cWN;
    short* lo = hi + cWN;
    const int i = (blockIdx.x * 256 + threadIdx.x) * 4;
    float4 v = *(const float4*)(W + i);
    float va[4] = {v.x, v.y, v.z, v.w};
    short4v h, l;
#pragma unroll
    for (int j = 0; j < 4; j++) {
        short hb = bfbits(va[j]);
        h[j] = hb;
        l[j] = bfbits(va[j] - bff(hb));
    }
    *(short4v*)(hi + i) = h;
    *(short4v*)(lo + i) = l;
}

// ---------------------------------------------------------------------------
// prep kernel: fused projection + Ev in ONE dispatch (concurrency via fusion).
//   blocks [0,768):   proj role. z=0 (Q), z=1 (K): pre-split bf16 hi/lo
//                     planes. z=2 (V): bf16 transposed VT. W pre-split.
//   blocks [768,2816): ev role.
// ---------------------------------------------------------------------------
__global__ __launch_bounds__(256) void prep_kernel(
    const float* __restrict__ q_in, const float* __restrict__ k_in,
    const float* __restrict__ v_in, const short* __restrict__ Wsp,
    const float* __restrict__ bq, const float* __restrict__ bk,
    const float* __restrict__ bv,
    const float* __restrict__ rel, const float* __restrict__ ts,
    const float* __restrict__ l1p, const float* __restrict__ l2p,
    float* __restrict__ ws, short* __restrict__ Evb)
{
    const int bid = blockIdx.x;
    const int tid = threadIdx.x;
    const int w    = tid >> 6;
    const int lane = tid & 63;

    if (bid < 768) {
        const int z  = bid >> 8;
        const int bx = bid & 255;
        const float* X    = (z == 0) ? q_in : (z == 1) ? k_in : v_in;
        const float* bias = (z == 0) ? bq   : (z == 1) ? bk   : bv;
        const short* Whi = Wsp + (size_t)z * 2 * cWN;
        const short* Wlo = Whi + cWN;
        short* HI  = (short*)ws + (size_t)z * 2 * cNE;
        short* LO  = HI + cNE;
        short* VTb = (short*)(ws + 2 * cNE);

        const int n16  = lane & 15;
        const int quad = lane >> 4;
        const int i0 = bx * 32 + 16 * (w & 1);
        const int j0 = 128 * (w >> 1);

        const float* xrow = X + (size_t)(i0 + n16) * cD + quad * 8;
        short8v a_hi[8], a_lo[8];
#pragma unroll
        for (int c = 0; c < 8; c++) {
            float xa[8];
            *(float4*)&xa[0] = *(const float4*)(xrow + c * 32);
            *(float4*)&xa[4] = *(const float4*)(xrow + c * 32 + 4);
#pragma unroll
            for (int j = 0; j < 8; j++) {
                short hb = bfbits(xa[j]);
                a_hi[c][j] = hb;
                a_lo[c][j] = bfbits(xa[j] - bff(hb));
            }
        }

#pragma unroll
        for (int t = 0; t < 8; t++) {
            const int jb = j0 + t * 16;
            const size_t wbase = (size_t)(jb + n16) * cD + quad * 8;
            f32x4 acc = (f32x4){0.f, 0.f, 0.f, 0.f};
#pragma unroll
            for (int c = 0; c < 8; c++) {
                short8v b_hi = *(const short8v*)(Whi + wbase + c * 32);
                short8v b_lo = *(const short8v*)(Wlo + wbase + c * 32);
                acc = __builtin_amdgcn_mfma_f32_16x16x32_bf16(a_hi[c], b_hi, acc, 0, 0, 0);
                acc = __builtin_amdgcn_mfma_f32_16x16x32_bf16(a_hi[c], b_lo, acc, 0, 0, 0);
                acc = __builtin_amdgcn_mfma_f32_16x16x32_bf16(a_lo[c], b_hi, acc, 0, 0, 0);
            }
            const int jg = jb + n16;
            const float bv_ = bias[jg];
            const int h_ = jg >> 5, dh = jg & 31;
            if (z == 2) {
#pragma unroll
                for (int r = 0; r < 4; r++) {
                    int gi = i0 + quad * 4 + r;
                    int b_ = gi >> 9, s_ = gi & 511;
                    VTb[(((size_t)(b_ * cH + h_)) * cDH + dh) * cS + s_] =
                        bfbits(acc[r] + bv_);
                }
            } else {
#pragma unroll
                for (int r = 0; r < 4; r++) {
                    int gi = i0 + quad * 4 + r;
                    int b_ = gi >> 9, s_ = gi & 511;
                    size_t idx = (((size_t)(b_ * cH + h_)) * cS + s_) * cDH + dh;
                    float v = acc[r] + bv_;
                    short hb2 = bfbits(v);
                    HI[idx] = hb2;
                    LO[idx] = bfbits(v - bff(hb2));
                }
            }
        }
    } else {
        const int row = (bid - 768) * 4 + w;          // b*512 + q
        const int q = row & 511;
        const float* tr = ts  + (size_t)row * cS;
        const float* rr = rel + (size_t)row * cS;
        const float l1 = l1p[0], l2 = l2p[0];
        const float Bc = (1.f - l1) * l2;
        const float Cc = l1;

        float tv[8], rv[8];
        float tmax = -1e30f, rmax = -1e30f;
#pragma unroll
        for (int j = 0; j < 8; j++) {
            int k = lane + 64 * j;
            float tl_ = (k <= q) ? tr[k] : 0.f;
            float r   = (k >  q) ? rr[k] : 0.f;
            tv[j] = (k <= q) ? __expf(-fabsf(tl_)) : -1e30f;
            rv[j] = (k > q && r != 0.f) ? r : -10000.f;
            tmax = fmaxf(tmax, tv[j]);
            rmax = fmaxf(rmax, rv[j]);
        }
#pragma unroll
        for (int m = 1; m < 64; m <<= 1) {
            tmax = fmaxf(tmax, __shfl_xor(tmax, m, 64));
            rmax = fmaxf(rmax, __shfl_xor(rmax, m, 64));
        }
        float te[8], re[8];
        float tsum = 0.f, rsum = 0.f;
#pragma unroll
        for (int j = 0; j < 8; j++) {
            te[j] = (tv[j] > -1e29f) ? __expf(tv[j] - tmax) : 0.f;
            re[j] = __expf(rv[j] - rmax);
            tsum += te[j]; rsum += re[j];
        }
#pragma unroll
        for (int m = 1; m < 64; m <<= 1) {
            tsum += __shfl_xor(tsum, m, 64);
            rsum += __shfl_xor(rsum, m, 64);
        }
        const float ti = Bc / tsum, ri = Cc / rsum;
#pragma unroll
        for (int j = 0; j < 8; j++) {
            int k = lane + 64 * j;
            Evb[(size_t)row * cS + k] = bfbits(te[j] * ti + re[j] * ri);
        }
    }
}

// ---------------------------------------------------------------------------
// Attention v8: 16-q-row blocks (was 32). LDS 34.3 KB -> 17.7 KB lifts
// residency 4 -> 6 blocks/CU (24 waves/CU, +50%) so other blocks' MFMA hides
// each block's blend-stream latency. Each of 4 waves covers 128 keys
// (8 tiles); softmax reduced across 4 waves; PV on waves 0-1, full k-range
// (FP order identical to v7). Causal skip, XCD remap, nt stores preserved.
// ---------------------------------------------------------------------------
__global__ __launch_bounds__(256, 6) void attn16_kernel(
    const float* __restrict__ ws, const short* __restrict__ Evb,
    const float* __restrict__ l1p, const float* __restrict__ l2p,
    float* __restrict__ out, float* __restrict__ prob)
{
    constexpr int PS = 536;
    __shared__ short Pl[16 * PS];                 // 17.2 KB
    __shared__ float redM[4][16];
    __shared__ float redS[4][16];

    const int tid  = threadIdx.x;
    const int w    = tid >> 6;
    const int lane = tid & 63;
    const int n16  = lane & 15;
    const int quad = lane >> 4;

    // XCD-aware remap over 4096 blocks: b = (flat&7) + 8*(slot>>8) keeps all
    // 256 blocks of batch b on XCD b&7 (bijective: slot = bhi|h|qt).
    const int flat = blockIdx.y * gridDim.x + blockIdx.x;   // 0..4095
    const int xcd  = flat & 7;
    const int slot = flat >> 3;                   // 0..511
    const int b  = xcd + 8 * (slot >> 8);         // 0..15
    const int h  = (slot >> 5) & 7;               // 0..7
    const int qt = slot & 31;                     // 0..31
    const size_t bh = (size_t)b * cH + h;
    const int q0 = qt * 16;

    const short* Qhi = (const short*)ws;
    const short* Qlo = Qhi + cNE;
    const short* Khi = Qhi + 2 * cNE;
    const short* Klo = Qhi + 3 * cNE;
    const short* VTb = (const short*)(ws + 2 * cNE);

    const float l1 = l1p[0], l2 = l2p[0];
    const float Ac = (1.f - l1) * (1.f - l2);

    const int kbase = 128 * w;                    // wave's 128-key span

    // ---- A fragment: 16 q rows, pre-split hi/lo ----
    const int rowA = q0 + n16;
    const size_t qoff = (bh * cS + rowA) * cDH + quad * 8;
    short8v a_hi = *(const short8v*)(Qhi + qoff);
    short8v a_lo = *(const short8v*)(Qlo + qoff);

    // ---- QK^T: 8 key tiles, statically unrolled, uniform causal skip ----
    const int tl = (kbase <= q0 + 15) ? min(7, (q0 + 15 - kbase) >> 4) : -1;
    f32x4 acc[8];
#pragma unroll
    for (int t = 0; t < 8; t++) {
        acc[t] = (f32x4){0.f, 0.f, 0.f, 0.f};
        if (t <= tl) {
            const size_t koff = (bh * cS + kbase + 16 * t + n16) * cDH + quad * 8;
            short8v b_hi = *(const short8v*)(Khi + koff);
            short8v b_lo = *(const short8v*)(Klo + koff);
            acc[t] = __builtin_amdgcn_mfma_f32_16x16x32_bf16(a_hi, b_hi, acc[t], 0, 0, 0);
            acc[t] = __builtin_amdgcn_mfma_f32_16x16x32_bf16(a_hi, b_lo, acc[t], 0, 0, 0);
            acc[t] = __builtin_amdgcn_mfma_f32_16x16x32_bf16(a_lo, b_hi, acc[t], 0, 0, 0);
        }
    }

    // ---- mask + scale + row max (rows q0 + rowDl + r, rowDl = quad*4) ----
    const float scale = 0.17677669529663687f;
    const int rowDl = quad * 4;
    float Mx0 = -1e30f, Mx1 = -1e30f, Mx2 = -1e30f, Mx3 = -1e30f;
#pragma unroll
    for (int t = 0; t < 8; t++) {
        const int kg = kbase + 16 * t + n16;
        const int rg = q0 + rowDl;
        float s0 = (kg <= rg + 0) ? acc[t][0] * scale : -1e30f;
        float s1 = (kg <= rg + 1) ? acc[t][1] * scale : -1e30f;
        float s2 = (kg <= rg + 2) ? acc[t][2] * scale : -1e30f;
        float s3 = (kg <= rg + 3) ? acc[t][3] * scale : -1e30f;
        acc[t][0] = s0; acc[t][1] = s1; acc[t][2] = s2; acc[t][3] = s3;
        Mx0 = fmaxf(Mx0, s0); Mx1 = fmaxf(Mx1, s1);
        Mx2 = fmaxf(Mx2, s2); Mx3 = fmaxf(Mx3, s3);
    }
#pragma unroll
    for (int m = 1; m < 16; m <<= 1) {
        Mx0 = fmaxf(Mx0, __shfl_xor(Mx0, m, 64));
        Mx1 = fmaxf(Mx1, __shfl_xor(Mx1, m, 64));
        Mx2 = fmaxf(Mx2, __shfl_xor(Mx2, m, 64));
        Mx3 = fmaxf(Mx3, __shfl_xor(Mx3, m, 64));
    }
    if (n16 == 0) {
        redM[w][rowDl + 0] = Mx0; redM[w][rowDl + 1] = Mx1;
        redM[w][rowDl + 2] = Mx2; redM[w][rowDl + 3] = Mx3;
    }
    __syncthreads();
    float Mg0 = fmaxf(fmaxf(redM[0][rowDl + 0], redM[1][rowDl + 0]),
                      fmaxf(redM[2][rowDl + 0], redM[3][rowDl + 0]));
    float Mg1 = fmaxf(fmaxf(redM[0][rowDl + 1], redM[1][rowDl + 1]),
                      fmaxf(redM[2][rowDl + 1], redM[3][rowDl + 1]));
    float Mg2 = fmaxf(fmaxf(redM[0][rowDl + 2], redM[1][rowDl + 2]),
                      fmaxf(redM[2][rowDl + 2], redM[3][rowDl + 2]));
    float Mg3 = fmaxf(fmaxf(redM[0][rowDl + 3], redM[1][rowDl + 3]),
                      fmaxf(redM[2][rowDl + 3], redM[3][rowDl + 3]));

    // ---- exp + row sum ----
    float S0 = 0.f, S1 = 0.f, S2 = 0.f, S3 = 0.f;
#pragma unroll
    for (int t = 0; t < 8; t++) {
        float e0 = __expf(acc[t][0] - Mg0);
        float e1 = __expf(acc[t][1] - Mg1);
        float e2 = __expf(acc[t][2] - Mg2);
        float e3 = __expf(acc[t][3] - Mg3);
        acc[t][0] = e0; acc[t][1] = e1; acc[t][2] = e2; acc[t][3] = e3;
        S0 += e0; S1 += e1; S2 += e2; S3 += e3;
    }
#pragma unroll
    for (int m = 1; m < 16; m <<= 1) {
        S0 += __shfl_xor(S0, m, 64); S1 += __shfl_xor(S1, m, 64);
        S2 += __shfl_xor(S2, m, 64); S3 += __shfl_xor(S3, m, 64);
    }
    if (n16 == 0) {
        redS[w][rowDl + 0] = S0; redS[w][rowDl + 1] = S1;
        redS[w][rowDl + 2] = S2; redS[w][rowDl + 3] = S3;
    }
    __syncthreads();
    const float i0 = Ac / (redS[0][rowDl + 0] + redS[1][rowDl + 0] +
                           redS[2][rowDl + 0] + redS[3][rowDl + 0]);
    const float i1 = Ac / (redS[0][rowDl + 1] + redS[1][rowDl + 1] +
                           redS[2][rowDl + 1] + redS[3][rowDl + 1]);
    const float i2 = Ac / (redS[0][rowDl + 2] + redS[1][rowDl + 2] +
                           redS[2][rowDl + 2] + redS[3][rowDl + 2]);
    const float i3 = Ac / (redS[0][rowDl + 3] + redS[1][rowDl + 3] +
                           redS[2][rowDl + 3] + redS[3][rowDl + 3]);

    // ---- store softmax part to P (bf16) ----
#pragma unroll
    for (int t = 0; t < 8; t++) {
        const int col = kbase + 16 * t + n16;
        Pl[(rowDl + 0) * PS + col] = bfbits(acc[t][0] * i0);
        Pl[(rowDl + 1) * PS + col] = bfbits(acc[t][1] * i1);
        Pl[(rowDl + 2) * PS + col] = bfbits(acc[t][2] * i2);
        Pl[(rowDl + 3) * PS + col] = bfbits(acc[t][3] * i3);
    }
    __syncthreads();

    // ---- blend with Ev + contiguous nontemporal prob write + P write-back ----
#pragma unroll
    for (int it = 0; it < 8; it++) {
        const int idx = it * 256 + tid;           // 0..2047
        const int r = idx >> 7;                   // 0..15
        const int c0 = (idx & 127) * 4;           // 0..508
        short* pp = &Pl[r * PS + c0];
        short4v pv = *(short4v*)pp;
        const short4v ev = *(const short4v*)(Evb + ((size_t)(b * cS + q0 + r)) * cS + c0);
        f32x4 o;
#pragma unroll
        for (int j = 0; j < 4; j++) o[j] = bff(pv[j]) + bff(ev[j]);
        __builtin_nontemporal_store(o, (f32x4*)(prob + (bh * cS + q0 + r) * cS + c0));
#pragma unroll
        for (int j = 0; j < 4; j++) pv[j] = bfbits(o[j]);
        *(short4v*)pp = pv;
    }
    __syncthreads();

    // ---- PV: out tile = 32 dh x 16 q; waves 0-1 each own a 16-dh half,
    // full k-range (same FP order as v7). Waves 2-3 idle (PV is short).
    if (w < 2) {
        const int dhA = 16 * w + n16;
        const short* vtrow = VTb + (bh * cDH + dhA) * cS;
        f32x4 oacc = (f32x4){0.f, 0.f, 0.f, 0.f};
#pragma unroll
        for (int k0 = 0; k0 < cS; k0 += 32) {
            short8v av = *(const short8v*)(vtrow + k0 + quad * 8);
            short8v bv = *(short8v*)&Pl[n16 * PS + k0 + quad * 8];
            oacc = __builtin_amdgcn_mfma_f32_16x16x32_bf16(av, bv, oacc, 0, 0, 0);
        }
        const int qg = q0 + n16;
        const int dhD = 16 * w + quad * 4;
        float* op = out + ((size_t)b * cS + qg) * cD + h * cDH + dhD;
        __builtin_nontemporal_store(oacc, (f32x4*)op);
    }
}

extern "C" void kernel_launch(void* const* d_in, const int* in_sizes, int n_in,
                              void* d_out, int out_size, void* d_ws, size_t ws_size,
                              hipStream_t stream) {
    const float* query = (const float*)d_in[0];
    const float* key   = (const float*)d_in[1];
    const float* value = (const float*)d_in[2];
    const float* rel   = (const float*)d_in[3];
    const float* tsp   = (const float*)d_in[4];
    const float* l1 = (const float*)d_in[6];
    const float* l2 = (const float*)d_in[7];
    const float* Wq = (const float*)d_in[8];
    const float* bq = (const float*)d_in[9];
    const float* Wk = (const float*)d_in[10];
    const float* bk = (const float*)d_in[11];
    const float* Wv = (const float*)d_in[12];
    const float* bv = (const float*)d_in[13];

    float* ws   = (float*)d_ws;
    short* Evb  = (short*)(ws + 3 * cNE);                 // bf16, 8.4 MB
    short* Wsp  = Evb + (size_t)cB * cS * cS;             // bf16 hi/lo W, 786 KB
    float* out  = (float*)d_out;
    float* prob = out + cNE;

    wsplit_kernel<<<dim3(64, 3), 256, 0, stream>>>(Wq, Wk, Wv, Wsp);
    prep_kernel<<<dim3(2816), 256, 0, stream>>>(query, key, value, Wsp,
                                                bq, bk, bv, rel, tsp,
                                                l1, l2, ws, Evb);
    attn16_kernel<<<dim3(32, 128), 256, 0, stream>>>(ws, Evb, l1, l2, out, prob);
}